// Round 1
// baseline (338.162 us; speedup 1.0000x reference)
//
#include <hip/hip_runtime.h>
#include <math.h>

#define EPSBN 1e-5f

constexpr int NROWS = 8192;   // N (and M)
constexpr int D0 = 256;
constexpr int F1 = 128;
constexpr int F2 = 64;
constexpr int TOT = 2 * NROWS;
constexpr int NCLS = 10;
constexpr int R1 = 16;            // rows/block, layer1
constexpr int R2 = 16;            // rows/block, layer2
constexpr int NB1 = TOT / R1;     // 1024
constexpr int NB2 = TOT / R2;     // 1024
constexpr int MSPLIT = 4;
constexpr int MLEN = NROWS / MSPLIT;  // 2048

// workspace offsets (in floats)
constexpr size_t OFF_W0T = 0;
constexpr size_t OFF_H1  = OFF_W0T + (size_t)D0 * F1;          // 32768
constexpr size_t OFF_P1S = OFF_H1  + (size_t)TOT * F1;
constexpr size_t OFF_P1Q = OFF_P1S + (size_t)NB1 * F1;
constexpr size_t OFF_SC0 = OFF_P1Q + (size_t)NB1 * F1;
constexpr size_t OFF_SH0 = OFF_SC0 + 2 * F1;
constexpr size_t OFF_W1E = OFF_SH0 + 2 * F1;
constexpr size_t OFF_B1E = OFF_W1E + (size_t)2 * F1 * F2;
constexpr size_t OFF_H2  = OFF_B1E + 2 * F2;
constexpr size_t OFF_P2S = OFF_H2  + (size_t)TOT * F2;
constexpr size_t OFF_P2Q = OFF_P2S + (size_t)NB2 * F2;
constexpr size_t OFF_SC1 = OFF_P2Q + (size_t)NB2 * F2;
constexpr size_t OFF_SH1 = OFF_SC1 + 2 * F2;
constexpr size_t OFF_QK  = OFF_SH1 + 2 * F2;
constexpr size_t OFF_RN  = OFF_QK  + (size_t)TOT * F2;
constexpr size_t OFF_SP  = OFF_RN  + TOT;
constexpr size_t OFF_CP  = OFF_SP  + (size_t)MSPLIT * NROWS;
// total = OFF_CP + MSPLIT*NROWS*NCLS  ≈ 5.01M floats ≈ 19.2 MiB

// ---------------- W0 transpose: W0T[t][j] = W0[j][t] ----------------
__global__ void k_w0t(const float* __restrict__ w0, float* __restrict__ w0t) {
  int idx = blockIdx.x * 256 + threadIdx.x;   // 32768
  int j = idx >> 8, t = idx & 255;
  w0t[t * F1 + j] = w0[idx];
}

// ---------------- layer 1: H1 = tanh(X @ W0^T + b0) ----------------
__global__ __launch_bounds__(128) void k_layer1(
    const float* __restrict__ x, const float* __restrict__ xn,
    const float* __restrict__ w0t, const float* __restrict__ b0,
    float* __restrict__ h1, float* __restrict__ p1s, float* __restrict__ p1q)
{
  __shared__ float xs[R1][D0];   // 16 KB
  const int blk = blockIdx.x;
  const int row0 = blk * R1;
  const float* src = (row0 < NROWS) ? (x + (size_t)row0 * D0)
                                    : (xn + (size_t)(row0 - NROWS) * D0);
  const float4* s4 = (const float4*)src;
  float4* x4 = (float4*)&xs[0][0];
  #pragma unroll
  for (int l = 0; l < 8; ++l) x4[threadIdx.x + l * 128] = s4[threadIdx.x + l * 128];
  __syncthreads();

  const int j = threadIdx.x;
  float acc[R1];
  #pragma unroll
  for (int r = 0; r < R1; ++r) acc[r] = 0.f;
  for (int t4 = 0; t4 < D0 / 4; ++t4) {
    const float w0_ = w0t[(t4 * 4 + 0) * F1 + j];
    const float w1_ = w0t[(t4 * 4 + 1) * F1 + j];
    const float w2_ = w0t[(t4 * 4 + 2) * F1 + j];
    const float w3_ = w0t[(t4 * 4 + 3) * F1 + j];
    #pragma unroll
    for (int r = 0; r < R1; ++r) {
      float4 xv = *(const float4*)&xs[r][t4 * 4];
      acc[r] = fmaf(xv.x, w0_, acc[r]);
      acc[r] = fmaf(xv.y, w1_, acc[r]);
      acc[r] = fmaf(xv.z, w2_, acc[r]);
      acc[r] = fmaf(xv.w, w3_, acc[r]);
    }
  }
  const float bj = b0[j];
  float ps = 0.f, pq = 0.f;
  #pragma unroll
  for (int r = 0; r < R1; ++r) {
    float v = tanhf(acc[r] + bj);
    h1[(size_t)(row0 + r) * F1 + j] = v;
    ps += v; pq += v * v;
  }
  p1s[(size_t)blk * F1 + j] = ps;
  p1q[(size_t)blk * F1 + j] = pq;
}

// ---- reduce layer-1 stats -> scale0/shift0 per (batch, feature) ----
__global__ __launch_bounds__(64) void k_red1(
    const float* __restrict__ p1s, const float* __restrict__ p1q,
    const float* __restrict__ g0, const float* __restrict__ bt0,
    float* __restrict__ sc0, float* __restrict__ sh0)
{
  const int b = blockIdx.x >> 7;      // 256 blocks: 2 x 128
  const int j = blockIdx.x & 127;
  const int t = threadIdx.x;
  float s = 0.f, q = 0.f;
  for (int i = t; i < NB1 / 2; i += 64) {
    s += p1s[(size_t)(b * (NB1 / 2) + i) * F1 + j];
    q += p1q[(size_t)(b * (NB1 / 2) + i) * F1 + j];
  }
  #pragma unroll
  for (int off = 32; off; off >>= 1) { s += __shfl_xor(s, off); q += __shfl_xor(q, off); }
  if (t == 0) {
    float m = s / (float)NROWS;
    float v = q / (float)NROWS - m * m;
    float sc = g0[j] * rsqrtf(v + EPSBN);
    sc0[b * F1 + j] = sc;
    sh0[b * F1 + j] = bt0[j] - m * sc;
  }
}

// ---- fold BN1 affine into W1: W1effT[b][j][o], b1eff[b][o] ----
__global__ __launch_bounds__(128) void k_fold(
    const float* __restrict__ w1, const float* __restrict__ b1,
    const float* __restrict__ sc0, const float* __restrict__ sh0,
    float* __restrict__ w1e, float* __restrict__ b1e)
{
  const int tid = threadIdx.x;      // 128 = 2 x 64
  const int b = tid >> 6, o = tid & 63;
  float acc = 0.f;
  for (int j = 0; j < F1; ++j) {
    float w = w1[o * F1 + j];
    w1e[(size_t)b * F1 * F2 + j * F2 + o] = w * sc0[b * F1 + j];
    acc += w * sh0[b * F1 + j];
  }
  b1e[b * F2 + o] = b1[o] + acc;
}

// ---------------- layer 2: H2 = tanh(H1 @ W1eff^T + b1eff) ----------------
__global__ __launch_bounds__(64) void k_layer2(
    const float* __restrict__ h1, const float* __restrict__ w1e, const float* __restrict__ b1e,
    float* __restrict__ h2, float* __restrict__ p2s, float* __restrict__ p2q)
{
  __shared__ float hs[R2][F1];   // 8 KB
  const int blk = blockIdx.x;
  const int row0 = blk * R2;
  const int b = (row0 >= NROWS) ? 1 : 0;
  const float4* s4 = (const float4*)(h1 + (size_t)row0 * F1);
  float4* x4 = (float4*)&hs[0][0];
  #pragma unroll
  for (int l = 0; l < 8; ++l) x4[threadIdx.x + l * 64] = s4[threadIdx.x + l * 64];
  __syncthreads();

  const int o = threadIdx.x;
  const float* wb = w1e + (size_t)b * F1 * F2;
  float acc[R2];
  #pragma unroll
  for (int r = 0; r < R2; ++r) acc[r] = 0.f;
  for (int t4 = 0; t4 < F1 / 4; ++t4) {
    const float w0_ = wb[(t4 * 4 + 0) * F2 + o];
    const float w1_ = wb[(t4 * 4 + 1) * F2 + o];
    const float w2_ = wb[(t4 * 4 + 2) * F2 + o];
    const float w3_ = wb[(t4 * 4 + 3) * F2 + o];
    #pragma unroll
    for (int r = 0; r < R2; ++r) {
      float4 xv = *(const float4*)&hs[r][t4 * 4];
      acc[r] = fmaf(xv.x, w0_, acc[r]);
      acc[r] = fmaf(xv.y, w1_, acc[r]);
      acc[r] = fmaf(xv.z, w2_, acc[r]);
      acc[r] = fmaf(xv.w, w3_, acc[r]);
    }
  }
  const float bj = b1e[b * F2 + o];
  float ps = 0.f, pq = 0.f;
  #pragma unroll
  for (int r = 0; r < R2; ++r) {
    float v = tanhf(acc[r] + bj);
    h2[(size_t)(row0 + r) * F2 + o] = v;
    ps += v; pq += v * v;
  }
  p2s[(size_t)blk * F2 + o] = ps;
  p2q[(size_t)blk * F2 + o] = pq;
}

// ---- reduce layer-2 stats -> scale1/shift1 ----
__global__ __launch_bounds__(64) void k_red2(
    const float* __restrict__ p2s, const float* __restrict__ p2q,
    const float* __restrict__ g1, const float* __restrict__ bt1,
    float* __restrict__ sc1, float* __restrict__ sh1)
{
  const int b = blockIdx.x >> 6;      // 128 blocks: 2 x 64
  const int o = blockIdx.x & 63;
  const int t = threadIdx.x;
  float s = 0.f, q = 0.f;
  for (int i = t; i < NB2 / 2; i += 64) {
    s += p2s[(size_t)(b * (NB2 / 2) + i) * F2 + o];
    q += p2q[(size_t)(b * (NB2 / 2) + i) * F2 + o];
  }
  #pragma unroll
  for (int off = 32; off; off >>= 1) { s += __shfl_xor(s, off); q += __shfl_xor(q, off); }
  if (t == 0) {
    float m = s / (float)NROWS;
    float v = q / (float)NROWS - m * m;
    float sc = g1[o] * rsqrtf(v + EPSBN);
    sc1[b * F2 + o] = sc;
    sh1[b * F2 + o] = bt1[o] - m * sc;
  }
}

// ---- apply BN2 -> qk features; per-row squared norms ----
__global__ __launch_bounds__(256) void k_bn2(
    const float* __restrict__ h2, const float* __restrict__ sc1, const float* __restrict__ sh1,
    float* __restrict__ qkv, float* __restrict__ rnorm)
{
  const int tid = threadIdx.x;
  const int r = tid >> 6, o = tid & 63;
  const int row = blockIdx.x * 4 + r;
  const int b = row >> 13;
  float v = sc1[b * F2 + o] * h2[(size_t)row * F2 + o] + sh1[b * F2 + o];
  qkv[(size_t)row * F2 + o] = v;
  float sq = v * v;
  #pragma unroll
  for (int off = 32; off; off >>= 1) sq += __shfl_xor(sq, off);
  if (o == 0) rnorm[row] = sq;
}

// ---------------- fused cdist + exp + class aggregation ----------------
// swizzled LDS layout: element (row r, dim kk) at  kk*64 + ((r>>2 ^ (kk&15))<<2) + (r&3)
__global__ __launch_bounds__(256) void k_dist(
    const float* __restrict__ qkv, const float* __restrict__ rn, const int* __restrict__ yn,
    float* __restrict__ sp, float* __restrict__ cp)
{
  __shared__ float qs[64 * 64];
  __shared__ float ks[64 * 64];
  __shared__ float kn[64];
  __shared__ int   ys[64];
  const int tid = threadIdx.x;
  const int tx = tid & 15, ty = tid >> 4;
  const int n0 = blockIdx.x * 64;
  const int split = blockIdx.y;

  {  // load q tile, transposed+swizzled
    const int c4 = tid & 15, rb = tid >> 4;
    #pragma unroll
    for (int l = 0; l < 4; ++l) {
      const int r = rb + l * 16;
      float4 g = *(const float4*)(qkv + (size_t)(n0 + r) * F2 + (c4 << 2));
      const int gr = r >> 2, e = r & 3, k0 = c4 << 2;
      qs[(k0 + 0) * 64 + ((gr ^ ((k0 + 0) & 15)) << 2) + e] = g.x;
      qs[(k0 + 1) * 64 + ((gr ^ ((k0 + 1) & 15)) << 2) + e] = g.y;
      qs[(k0 + 2) * 64 + ((gr ^ ((k0 + 2) & 15)) << 2) + e] = g.z;
      qs[(k0 + 3) * 64 + ((gr ^ ((k0 + 3) & 15)) << 2) + e] = g.w;
    }
  }
  float qn[4];
  #pragma unroll
  for (int r = 0; r < 4; ++r) qn[r] = rn[n0 + (ty << 2) + r];

  float s_acc[4] = {0.f, 0.f, 0.f, 0.f};
  float cls[4][NCLS];
  #pragma unroll
  for (int r = 0; r < 4; ++r)
    #pragma unroll
    for (int c = 0; c < NCLS; ++c) cls[r][c] = 0.f;

  for (int mt = 0; mt < MLEN / 64; ++mt) {
    const int m0 = split * MLEN + mt * 64;
    __syncthreads();
    {  // load k tile, transposed+swizzled
      const int c4 = tid & 15, rb = tid >> 4;
      #pragma unroll
      for (int l = 0; l < 4; ++l) {
        const int r = rb + l * 16;
        float4 g = *(const float4*)(qkv + (size_t)(NROWS + m0 + r) * F2 + (c4 << 2));
        const int gr = r >> 2, e = r & 3, k0 = c4 << 2;
        ks[(k0 + 0) * 64 + ((gr ^ ((k0 + 0) & 15)) << 2) + e] = g.x;
        ks[(k0 + 1) * 64 + ((gr ^ ((k0 + 1) & 15)) << 2) + e] = g.y;
        ks[(k0 + 2) * 64 + ((gr ^ ((k0 + 2) & 15)) << 2) + e] = g.z;
        ks[(k0 + 3) * 64 + ((gr ^ ((k0 + 3) & 15)) << 2) + e] = g.w;
      }
      if (tid < 64) {
        kn[tid] = rn[NROWS + m0 + tid];
        ys[tid] = yn[m0 + tid];
      }
    }
    __syncthreads();

    float dot[4][4];
    #pragma unroll
    for (int r = 0; r < 4; ++r) { dot[r][0] = 0.f; dot[r][1] = 0.f; dot[r][2] = 0.f; dot[r][3] = 0.f; }
    #pragma unroll 4
    for (int kk = 0; kk < 64; ++kk) {
      const float4 a = *(const float4*)&qs[kk * 64 + ((ty ^ (kk & 15)) << 2)];
      const float4 b = *(const float4*)&ks[kk * 64 + ((tx ^ (kk & 15)) << 2)];
      dot[0][0] = fmaf(a.x, b.x, dot[0][0]); dot[0][1] = fmaf(a.x, b.y, dot[0][1]);
      dot[0][2] = fmaf(a.x, b.z, dot[0][2]); dot[0][3] = fmaf(a.x, b.w, dot[0][3]);
      dot[1][0] = fmaf(a.y, b.x, dot[1][0]); dot[1][1] = fmaf(a.y, b.y, dot[1][1]);
      dot[1][2] = fmaf(a.y, b.z, dot[1][2]); dot[1][3] = fmaf(a.y, b.w, dot[1][3]);
      dot[2][0] = fmaf(a.z, b.x, dot[2][0]); dot[2][1] = fmaf(a.z, b.y, dot[2][1]);
      dot[2][2] = fmaf(a.z, b.z, dot[2][2]); dot[2][3] = fmaf(a.z, b.w, dot[2][3]);
      dot[3][0] = fmaf(a.w, b.x, dot[3][0]); dot[3][1] = fmaf(a.w, b.y, dot[3][1]);
      dot[3][2] = fmaf(a.w, b.z, dot[3][2]); dot[3][3] = fmaf(a.w, b.w, dot[3][3]);
    }

    #pragma unroll
    for (int t = 0; t < 4; ++t) {
      const int col = (tx << 2) + t;
      const int y = ys[col];
      const float knt = kn[col];
      float u[4];
      #pragma unroll
      for (int r = 0; r < 4; ++r) {
        float d2 = fmaf(-2.f, dot[r][t], qn[r] + knt);
        d2 = fmaxf(d2, 1e-12f);
        float uu = __expf(-sqrtf(d2));
        u[r] = uu;
        s_acc[r] += uu;
      }
      #pragma unroll
      for (int c = 0; c < NCLS; ++c) {
        const bool p = (y == c);
        #pragma unroll
        for (int r = 0; r < 4; ++r) cls[r][c] += p ? u[r] : 0.f;
      }
    }
  }

  // reduce across the 16 tx lanes (contiguous lanes within a 16-lane group)
  #pragma unroll
  for (int off = 1; off < 16; off <<= 1) {
    #pragma unroll
    for (int r = 0; r < 4; ++r) {
      s_acc[r] += __shfl_xor(s_acc[r], off);
      #pragma unroll
      for (int c = 0; c < NCLS; ++c) cls[r][c] += __shfl_xor(cls[r][c], off);
    }
  }
  if (tx == 0) {
    #pragma unroll
    for (int r = 0; r < 4; ++r) {
      const int n = n0 + (ty << 2) + r;
      sp[(size_t)split * NROWS + n] = s_acc[r];
      #pragma unroll
      for (int c = 0; c < NCLS; ++c)
        cp[((size_t)split * NROWS + n) * NCLS + c] = cls[r][c];
    }
  }
}

// ---- combine m-splits, normalize, clip ----
__global__ void k_final(const float* __restrict__ sp, const float* __restrict__ cp,
                        float* __restrict__ out)
{
  const int idx = blockIdx.x * 256 + threadIdx.x;
  if (idx >= NROWS * NCLS) return;
  const int n = idx / NCLS, c = idx - n * NCLS;
  float s = sp[n] + sp[NROWS + n] + sp[2 * NROWS + n] + sp[3 * NROWS + n];
  float v = cp[(size_t)n * NCLS + c]
          + cp[((size_t)NROWS + n) * NCLS + c]
          + cp[((size_t)2 * NROWS + n) * NCLS + c]
          + cp[((size_t)3 * NROWS + n) * NCLS + c];
  v /= s;
  out[idx] = fminf(fmaxf(v, 0.f), 1.f);
}

extern "C" void kernel_launch(void* const* d_in, const int* in_sizes, int n_in,
                              void* d_out, int out_size, void* d_ws, size_t ws_size,
                              hipStream_t stream) {
  const float* x   = (const float*)d_in[0];
  const float* xn  = (const float*)d_in[1];
  const int*   yn  = (const int*)d_in[2];
  const float* W0  = (const float*)d_in[3];
  const float* b0  = (const float*)d_in[4];
  const float* g0  = (const float*)d_in[5];
  const float* bt0 = (const float*)d_in[6];
  const float* W1  = (const float*)d_in[7];
  const float* b1  = (const float*)d_in[8];
  const float* g1  = (const float*)d_in[9];
  const float* bt1 = (const float*)d_in[10];
  float* out = (float*)d_out;
  float* ws  = (float*)d_ws;

  float* w0tp = ws + OFF_W0T;
  float* h1p  = ws + OFF_H1;
  float* p1sp = ws + OFF_P1S;
  float* p1qp = ws + OFF_P1Q;
  float* sc0p = ws + OFF_SC0;
  float* sh0p = ws + OFF_SH0;
  float* w1ep = ws + OFF_W1E;
  float* b1ep = ws + OFF_B1E;
  float* h2p  = ws + OFF_H2;
  float* p2sp = ws + OFF_P2S;
  float* p2qp = ws + OFF_P2Q;
  float* sc1p = ws + OFF_SC1;
  float* sh1p = ws + OFF_SH1;
  float* qkp  = ws + OFF_QK;
  float* rnp  = ws + OFF_RN;
  float* spp  = ws + OFF_SP;
  float* cpp  = ws + OFF_CP;

  k_w0t<<<128, 256, 0, stream>>>(W0, w0tp);
  k_layer1<<<NB1, 128, 0, stream>>>(x, xn, w0tp, b0, h1p, p1sp, p1qp);
  k_red1<<<256, 64, 0, stream>>>(p1sp, p1qp, g0, bt0, sc0p, sh0p);
  k_fold<<<1, 128, 0, stream>>>(W1, b1, sc0p, sh0p, w1ep, b1ep);
  k_layer2<<<NB2, 64, 0, stream>>>(h1p, w1ep, b1ep, h2p, p2sp, p2qp);
  k_red2<<<128, 64, 0, stream>>>(p2sp, p2qp, g1, bt1, sc1p, sh1p);
  k_bn2<<<TOT / 4, 256, 0, stream>>>(h2p, sc1p, sh1p, qkp, rnp);
  k_dist<<<dim3(NROWS / 64, MSPLIT), 256, 0, stream>>>(qkp, rnp, yn, spp, cpp);
  k_final<<<(NROWS * NCLS + 255) / 256, 256, 0, stream>>>(spp, cpp, out);
}

// Round 2
// 181.311 us; speedup vs baseline: 1.8651x; 1.8651x over previous
//
#include <hip/hip_runtime.h>
#include <math.h>

#define EPSBN 1e-5f

typedef unsigned short u16;
typedef short bf16x8 __attribute__((ext_vector_type(8)));
typedef float f32x4 __attribute__((ext_vector_type(4)));
typedef int i32x4 __attribute__((ext_vector_type(4)));

constexpr int NROWS = 8192;   // N (and M)
constexpr int D0 = 256;
constexpr int F1 = 128;
constexpr int F2 = 64;
constexpr int TOT = 2 * NROWS;
constexpr int NCLS = 10;
constexpr int R1 = 16;
constexpr int R2 = 16;
constexpr int NB1 = TOT / R1;     // 1024
constexpr int NB2 = TOT / R2;     // 1024
constexpr int MPAD = 8832;        // 138 tiles of 64 (max padded M)
constexpr int NT_PAD = MPAD / 64; // 138
constexpr int GY = 12;            // m-tile groups (12 tiles each, last=6)

// workspace offsets (floats)
constexpr size_t OFF_W0T = 0;
constexpr size_t OFF_H1  = 32768;
constexpr size_t OFF_P1S = OFF_H1  + (size_t)TOT * F1;            // 2129920
constexpr size_t OFF_P1Q = OFF_P1S + (size_t)NB1 * F1;
constexpr size_t OFF_SC0 = OFF_P1Q + (size_t)NB1 * F1;
constexpr size_t OFF_SH0 = OFF_SC0 + 2 * F1;
constexpr size_t OFF_W1E = OFF_SH0 + 2 * F1;
constexpr size_t OFF_B1E = OFF_W1E + (size_t)2 * F1 * F2;
constexpr size_t OFF_H2  = OFF_B1E + 2 * F2;
constexpr size_t OFF_P2S = OFF_H2  + (size_t)TOT * F2;
constexpr size_t OFF_P2Q = OFF_P2S + (size_t)NB2 * F2;
constexpr size_t OFF_SC1 = OFF_P2Q + (size_t)NB2 * F2;
constexpr size_t OFF_SH1 = OFF_SC1 + 2 * F2;
constexpr size_t OFF_QH  = OFF_SH1 + 2 * F2;                      // ushort[8192*64]
constexpr size_t OFF_QL  = OFF_QH  + (size_t)NROWS * 32;
constexpr size_t OFF_QN2 = OFF_QL  + (size_t)NROWS * 32;
constexpr size_t OFF_KH  = OFF_QN2 + NROWS;                       // ushort[8832*64]
constexpr size_t OFF_KL  = OFF_KH  + (size_t)MPAD * 32;
constexpr size_t OFF_KN2 = OFF_KL  + (size_t)MPAD * 32;
constexpr size_t OFF_PIDX= OFF_KN2 + MPAD;                        // int[8832]
constexpr size_t OFF_TCLS= OFF_PIDX+ MPAD;                        // int[160]
constexpr size_t OFF_PART= OFF_H1;  // alias: h1 dead after layer2; 12*11*8192 <= TOT*F1

__device__ inline u16 f2bf(float f) {
  unsigned u = __float_as_uint(f);
  unsigned r = (u + 0x7fffu + ((u >> 16) & 1u)) >> 16;
  return (u16)r;
}
__device__ inline float bf2f(u16 h) { return __uint_as_float(((unsigned)h) << 16); }

// ---------------- W0 transpose ----------------
__global__ void k_w0t(const float* __restrict__ w0, float* __restrict__ w0t) {
  int idx = blockIdx.x * 256 + threadIdx.x;   // 32768
  int j = idx >> 8, t = idx & 255;
  w0t[t * F1 + j] = w0[idx];
}

// ---------------- layer 1 ----------------
__global__ __launch_bounds__(128) void k_layer1(
    const float* __restrict__ x, const float* __restrict__ xn,
    const float* __restrict__ w0t, const float* __restrict__ b0,
    float* __restrict__ h1, float* __restrict__ p1s, float* __restrict__ p1q)
{
  __shared__ float xs[R1][D0];
  const int blk = blockIdx.x;
  const int row0 = blk * R1;
  const float* src = (row0 < NROWS) ? (x + (size_t)row0 * D0)
                                    : (xn + (size_t)(row0 - NROWS) * D0);
  const float4* s4 = (const float4*)src;
  float4* x4 = (float4*)&xs[0][0];
  #pragma unroll
  for (int l = 0; l < 8; ++l) x4[threadIdx.x + l * 128] = s4[threadIdx.x + l * 128];
  __syncthreads();

  const int j = threadIdx.x;
  float acc[R1];
  #pragma unroll
  for (int r = 0; r < R1; ++r) acc[r] = 0.f;
  for (int t4 = 0; t4 < D0 / 4; ++t4) {
    const float w0_ = w0t[(t4 * 4 + 0) * F1 + j];
    const float w1_ = w0t[(t4 * 4 + 1) * F1 + j];
    const float w2_ = w0t[(t4 * 4 + 2) * F1 + j];
    const float w3_ = w0t[(t4 * 4 + 3) * F1 + j];
    #pragma unroll
    for (int r = 0; r < R1; ++r) {
      float4 xv = *(const float4*)&xs[r][t4 * 4];
      acc[r] = fmaf(xv.x, w0_, acc[r]);
      acc[r] = fmaf(xv.y, w1_, acc[r]);
      acc[r] = fmaf(xv.z, w2_, acc[r]);
      acc[r] = fmaf(xv.w, w3_, acc[r]);
    }
  }
  const float bj = b0[j];
  float ps = 0.f, pq = 0.f;
  #pragma unroll
  for (int r = 0; r < R1; ++r) {
    float v = tanhf(acc[r] + bj);
    h1[(size_t)(row0 + r) * F1 + j] = v;
    ps += v; pq += v * v;
  }
  p1s[(size_t)blk * F1 + j] = ps;
  p1q[(size_t)blk * F1 + j] = pq;
}

__global__ __launch_bounds__(64) void k_red1(
    const float* __restrict__ p1s, const float* __restrict__ p1q,
    const float* __restrict__ g0, const float* __restrict__ bt0,
    float* __restrict__ sc0, float* __restrict__ sh0)
{
  const int b = blockIdx.x >> 7;
  const int j = blockIdx.x & 127;
  const int t = threadIdx.x;
  float s = 0.f, q = 0.f;
  for (int i = t; i < NB1 / 2; i += 64) {
    s += p1s[(size_t)(b * (NB1 / 2) + i) * F1 + j];
    q += p1q[(size_t)(b * (NB1 / 2) + i) * F1 + j];
  }
  #pragma unroll
  for (int off = 32; off; off >>= 1) { s += __shfl_xor(s, off); q += __shfl_xor(q, off); }
  if (t == 0) {
    float m = s / (float)NROWS;
    float v = q / (float)NROWS - m * m;
    float sc = g0[j] * rsqrtf(v + EPSBN);
    sc0[b * F1 + j] = sc;
    sh0[b * F1 + j] = bt0[j] - m * sc;
  }
}

__global__ __launch_bounds__(128) void k_fold(
    const float* __restrict__ w1, const float* __restrict__ b1,
    const float* __restrict__ sc0, const float* __restrict__ sh0,
    float* __restrict__ w1e, float* __restrict__ b1e)
{
  const int tid = threadIdx.x;
  const int b = tid >> 6, o = tid & 63;
  float acc = 0.f;
  for (int j = 0; j < F1; ++j) {
    float w = w1[o * F1 + j];
    w1e[(size_t)b * F1 * F2 + j * F2 + o] = w * sc0[b * F1 + j];
    acc += w * sh0[b * F1 + j];
  }
  b1e[b * F2 + o] = b1[o] + acc;
}

__global__ __launch_bounds__(64) void k_layer2(
    const float* __restrict__ h1, const float* __restrict__ w1e, const float* __restrict__ b1e,
    float* __restrict__ h2, float* __restrict__ p2s, float* __restrict__ p2q)
{
  __shared__ float hs[R2][F1];
  const int blk = blockIdx.x;
  const int row0 = blk * R2;
  const int b = (row0 >= NROWS) ? 1 : 0;
  const float4* s4 = (const float4*)(h1 + (size_t)row0 * F1);
  float4* x4 = (float4*)&hs[0][0];
  #pragma unroll
  for (int l = 0; l < 8; ++l) x4[threadIdx.x + l * 64] = s4[threadIdx.x + l * 64];
  __syncthreads();

  const int o = threadIdx.x;
  const float* wb = w1e + (size_t)b * F1 * F2;
  float acc[R2];
  #pragma unroll
  for (int r = 0; r < R2; ++r) acc[r] = 0.f;
  for (int t4 = 0; t4 < F1 / 4; ++t4) {
    const float w0_ = wb[(t4 * 4 + 0) * F2 + o];
    const float w1_ = wb[(t4 * 4 + 1) * F2 + o];
    const float w2_ = wb[(t4 * 4 + 2) * F2 + o];
    const float w3_ = wb[(t4 * 4 + 3) * F2 + o];
    #pragma unroll
    for (int r = 0; r < R2; ++r) {
      float4 xv = *(const float4*)&hs[r][t4 * 4];
      acc[r] = fmaf(xv.x, w0_, acc[r]);
      acc[r] = fmaf(xv.y, w1_, acc[r]);
      acc[r] = fmaf(xv.z, w2_, acc[r]);
      acc[r] = fmaf(xv.w, w3_, acc[r]);
    }
  }
  const float bj = b1e[b * F2 + o];
  float ps = 0.f, pq = 0.f;
  #pragma unroll
  for (int r = 0; r < R2; ++r) {
    float v = tanhf(acc[r] + bj);
    h2[(size_t)(row0 + r) * F2 + o] = v;
    ps += v; pq += v * v;
  }
  p2s[(size_t)blk * F2 + o] = ps;
  p2q[(size_t)blk * F2 + o] = pq;
}

__global__ __launch_bounds__(64) void k_red2(
    const float* __restrict__ p2s, const float* __restrict__ p2q,
    const float* __restrict__ g1, const float* __restrict__ bt1,
    float* __restrict__ sc1, float* __restrict__ sh1)
{
  const int b = blockIdx.x >> 6;
  const int o = blockIdx.x & 63;
  const int t = threadIdx.x;
  float s = 0.f, q = 0.f;
  for (int i = t; i < NB2 / 2; i += 64) {
    s += p2s[(size_t)(b * (NB2 / 2) + i) * F2 + o];
    q += p2q[(size_t)(b * (NB2 / 2) + i) * F2 + o];
  }
  #pragma unroll
  for (int off = 32; off; off >>= 1) { s += __shfl_xor(s, off); q += __shfl_xor(q, off); }
  if (t == 0) {
    float m = s / (float)NROWS;
    float v = q / (float)NROWS - m * m;
    float sc = g1[o] * rsqrtf(v + EPSBN);
    sc1[b * F2 + o] = sc;
    sh1[b * F2 + o] = bt1[o] - m * sc;
  }
}

// ---------------- stable counting sort of K rows by class, padded to 64 ----------------
__global__ __launch_bounds__(256) void k_sort(const int* __restrict__ yn,
                                              int* __restrict__ pidx, int* __restrict__ tcls)
{
  __shared__ int cnt[256][NCLS];
  __shared__ int wtot[4][NCLS];
  __shared__ int pstart[NCLS + 1];
  const int t = threadIdx.x;
  const int lane = t & 63, w = t >> 6;
  #pragma unroll
  for (int c = 0; c < NCLS; ++c) cnt[t][c] = 0;
  for (int i = t; i < MPAD; i += 256) pidx[i] = -1;
  const int base = t * 32;
  for (int i = 0; i < 32; ++i) cnt[t][yn[base + i]]++;
  __syncthreads();
  #pragma unroll
  for (int c = 0; c < NCLS; ++c) {
    int x = cnt[t][c];
    int inc = x;
    #pragma unroll
    for (int d = 1; d < 64; d <<= 1) { int y = __shfl_up(inc, d); if (lane >= d) inc += y; }
    if (lane == 63) wtot[w][c] = inc;
    cnt[t][c] = inc - x;   // exclusive within wave
  }
  __syncthreads();
  if (t == 0) {
    int run = 0;
    #pragma unroll
    for (int c = 0; c < NCLS; ++c) {
      int tot = wtot[0][c] + wtot[1][c] + wtot[2][c] + wtot[3][c];
      pstart[c] = run;
      int ntile = (tot + 63) >> 6;
      for (int tt = 0; tt < ntile; ++tt) tcls[(run >> 6) + tt] = c;
      run += ntile << 6;
    }
    pstart[NCLS] = run;
    for (int tt = run >> 6; tt < NT_PAD; ++tt) tcls[tt] = NCLS;
  }
  __syncthreads();
  #pragma unroll
  for (int c = 0; c < NCLS; ++c) {
    int add = pstart[c];
    for (int w2 = 0; w2 < 4; ++w2) if (w2 < w) add += wtot[w2][c];
    cnt[t][c] += add;
  }
  __syncthreads();
  for (int i = 0; i < 32; ++i) {
    int idx = base + i;
    int c = yn[idx];
    pidx[cnt[t][c]++] = idx;
  }
}

// ---------------- BN2 + bf16 split: Q side ----------------
__global__ __launch_bounds__(256) void k_bn2q(
    const float* __restrict__ h2, const float* __restrict__ sc1, const float* __restrict__ sh1,
    u16* __restrict__ qh, u16* __restrict__ ql, float* __restrict__ qn2)
{
  const int tid = threadIdx.x;
  const int r = tid >> 6, o = tid & 63;
  const int row = blockIdx.x * 4 + r;
  float v = sc1[o] * h2[(size_t)row * F2 + o] + sh1[o];
  u16 hi = f2bf(v);
  u16 lo = f2bf(v - bf2f(hi));
  qh[(size_t)row * F2 + o] = hi;
  ql[(size_t)row * F2 + o] = lo;
  float sq = v * v;
  #pragma unroll
  for (int off = 32; off; off >>= 1) sq += __shfl_xor(sq, off);
  if (o == 0) qn2[row] = sq;
}

// ---------------- BN2 + bf16 split: K side, permuted + padded ----------------
__global__ __launch_bounds__(256) void k_bn2k(
    const float* __restrict__ h2, const float* __restrict__ sc1, const float* __restrict__ sh1,
    const int* __restrict__ pidx,
    u16* __restrict__ kh, u16* __restrict__ kl, float* __restrict__ kn2)
{
  const int tid = threadIdx.x;
  const int r = tid >> 6, o = tid & 63;
  const int row = blockIdx.x * 4 + r;   // 0..8831
  const int src = pidx[row];
  float v = 0.f;
  if (src >= 0) v = sc1[F2 + o] * h2[(size_t)(NROWS + src) * F2 + o] + sh1[F2 + o];
  u16 hi = f2bf(v);
  u16 lo = f2bf(v - bf2f(hi));
  kh[(size_t)row * F2 + o] = hi;
  kl[(size_t)row * F2 + o] = lo;
  float sq = v * v;
  #pragma unroll
  for (int off = 32; off; off >>= 1) sq += __shfl_xor(sq, off);
  if (o == 0) kn2[row] = (src >= 0) ? sq : 1e30f;
}

// ---------------- MFMA cdist + exp + per-class accumulation ----------------
// LDS tile: for col i: 256B region; slot s (16B) holds (arr=s>>3, chunk cp=(s&7)^(i&7))
__global__ __launch_bounds__(256) void k_dist(
    const u16* __restrict__ qh, const u16* __restrict__ ql, const float* __restrict__ qn2,
    const u16* __restrict__ kh, const u16* __restrict__ kl, const float* __restrict__ kn2,
    const int* __restrict__ tcls, float* __restrict__ part)
{
  __shared__ u16 bs[64 * 128];              // 16 KB swizzled K tile
  __shared__ float cls_lds[(NCLS + 1) * 64];
  const int tid = threadIdx.x;
  const int l = tid & 63, w = tid >> 6;
  const int n0 = blockIdx.x * 64;
  const int g = blockIdx.y;
  const int t0 = g * 12;
  const int t1 = (t0 + 12 < NT_PAD) ? (t0 + 12) : NT_PAD;

  for (int i = tid; i < (NCLS + 1) * 64; i += 256) cls_lds[i] = 0.f;

  const int l15 = l & 15, l4 = l >> 4;
  // A fragments: rows n0+16w+l15, k = 8*l4 + i  (held in regs for whole kernel)
  const int arow = n0 + 16 * w + l15;
  const bf16x8 aH0 = *(const bf16x8*)(qh + (size_t)arow * 64 + l4 * 8);
  const bf16x8 aH1 = *(const bf16x8*)(qh + (size_t)arow * 64 + 32 + l4 * 8);
  const bf16x8 aL0 = *(const bf16x8*)(ql + (size_t)arow * 64 + l4 * 8);
  const bf16x8 aL1 = *(const bf16x8*)(ql + (size_t)arow * 64 + 32 + l4 * 8);
  const f32x4 qn = *(const f32x4*)(qn2 + n0 + 16 * w + l4 * 4);

  // staging: thread handles chunks q=j*256+tid -> col=16j+(tid>>4), ch=tid&15
  const ushort* arrp = ((tid >> 3) & 1) ? kl : kh;
  const int cp8 = (tid & 7) * 8;
  const int colb = tid >> 4;
  const int slot = ((tid >> 3) & 1) * 8 + ((tid & 7) ^ (colb & 7));
  char* dstb = (char*)bs + colb * 256 + slot * 16;

  // B-frag base byte offset (swizzled): col=16ct+l15, slot=(l4)^(l&7)
  const int P = l15 * 256 + ((l4 ^ (l & 7)) << 4);
  const char* bb = (const char*)bs;

  i32x4 st0, st1, st2, st3;
  {
    const int m0 = t0 * 64;
    st0 = *(const i32x4*)(arrp + (size_t)(m0 + colb) * 64 + cp8);
    st1 = *(const i32x4*)(arrp + (size_t)(m0 + 16 + colb) * 64 + cp8);
    st2 = *(const i32x4*)(arrp + (size_t)(m0 + 32 + colb) * 64 + cp8);
    st3 = *(const i32x4*)(arrp + (size_t)(m0 + 48 + colb) * 64 + cp8);
  }

  float run0 = 0.f, run1 = 0.f, run2 = 0.f, run3 = 0.f;
  int ccur = tcls[t0];

#define FLUSH(CC) { \
    run0 += __shfl_xor(run0, 1); run0 += __shfl_xor(run0, 2); run0 += __shfl_xor(run0, 4); run0 += __shfl_xor(run0, 8); \
    run1 += __shfl_xor(run1, 1); run1 += __shfl_xor(run1, 2); run1 += __shfl_xor(run1, 4); run1 += __shfl_xor(run1, 8); \
    run2 += __shfl_xor(run2, 1); run2 += __shfl_xor(run2, 2); run2 += __shfl_xor(run2, 4); run2 += __shfl_xor(run2, 8); \
    run3 += __shfl_xor(run3, 1); run3 += __shfl_xor(run3, 2); run3 += __shfl_xor(run3, 4); run3 += __shfl_xor(run3, 8); \
    if (l15 == 0) { \
      float* cl = cls_lds + (CC) * 64 + 16 * w + l4 * 4; \
      cl[0] += run0; cl[1] += run1; cl[2] += run2; cl[3] += run3; \
    } \
    run0 = run1 = run2 = run3 = 0.f; \
  }

#define CTSTEP(CT, ACC) { \
    const char* pp = bb + (CT) * 4096; \
    bf16x8 bh0 = *(const bf16x8*)(pp + P); \
    bf16x8 bh1 = *(const bf16x8*)(pp + (P ^ 64)); \
    bf16x8 bl0 = *(const bf16x8*)(pp + (P ^ 128)); \
    bf16x8 bl1 = *(const bf16x8*)(pp + (P ^ 192)); \
    ACC = __builtin_amdgcn_mfma_f32_16x16x32_bf16(aH0, bh0, ACC, 0, 0, 0); \
    ACC = __builtin_amdgcn_mfma_f32_16x16x32_bf16(aH1, bh1, ACC, 0, 0, 0); \
    ACC = __builtin_amdgcn_mfma_f32_16x16x32_bf16(aH0, bl0, ACC, 0, 0, 0); \
    ACC = __builtin_amdgcn_mfma_f32_16x16x32_bf16(aH1, bl1, ACC, 0, 0, 0); \
    ACC = __builtin_amdgcn_mfma_f32_16x16x32_bf16(aL0, bh0, ACC, 0, 0, 0); \
    ACC = __builtin_amdgcn_mfma_f32_16x16x32_bf16(aL1, bh1, ACC, 0, 0, 0); \
  }

#define EPI(ACC, KV) { \
    float d2, u; \
    d2 = fmaf(-2.f, ACC[0], qn[0] + (KV)); u = __expf(-sqrtf(fmaxf(d2, 1e-12f))); run0 += u; \
    d2 = fmaf(-2.f, ACC[1], qn[1] + (KV)); u = __expf(-sqrtf(fmaxf(d2, 1e-12f))); run1 += u; \
    d2 = fmaf(-2.f, ACC[2], qn[2] + (KV)); u = __expf(-sqrtf(fmaxf(d2, 1e-12f))); run2 += u; \
    d2 = fmaf(-2.f, ACC[3], qn[3] + (KV)); u = __expf(-sqrtf(fmaxf(d2, 1e-12f))); run3 += u; \
  }

  for (int t = t0; t < t1; ++t) {
    const int m0 = t * 64;
    __syncthreads();
    *(i32x4*)(dstb)         = st0;
    *(i32x4*)(dstb + 4096)  = st1;
    *(i32x4*)(dstb + 8192)  = st2;
    *(i32x4*)(dstb + 12288) = st3;
    __syncthreads();
    if (t + 1 < t1) {
      const int m1 = m0 + 64;
      st0 = *(const i32x4*)(arrp + (size_t)(m1 + colb) * 64 + cp8);
      st1 = *(const i32x4*)(arrp + (size_t)(m1 + 16 + colb) * 64 + cp8);
      st2 = *(const i32x4*)(arrp + (size_t)(m1 + 32 + colb) * 64 + cp8);
      st3 = *(const i32x4*)(arrp + (size_t)(m1 + 48 + colb) * 64 + cp8);
    }
    const float kv0 = kn2[m0 + l15];
    const float kv1 = kn2[m0 + 16 + l15];
    const float kv2 = kn2[m0 + 32 + l15];
    const float kv3 = kn2[m0 + 48 + l15];
    const int c = tcls[t];
    if (c != ccur) { FLUSH(ccur); ccur = c; }

    f32x4 acc0 = {0.f, 0.f, 0.f, 0.f};
    f32x4 acc1 = {0.f, 0.f, 0.f, 0.f};
    f32x4 acc2 = {0.f, 0.f, 0.f, 0.f};
    f32x4 acc3 = {0.f, 0.f, 0.f, 0.f};
    CTSTEP(0, acc0)
    CTSTEP(1, acc1)
    CTSTEP(2, acc2)
    CTSTEP(3, acc3)
    EPI(acc0, kv0)
    EPI(acc1, kv1)
    EPI(acc2, kv2)
    EPI(acc3, kv3)
  }
  FLUSH(ccur);
  __syncthreads();

  for (int i = tid; i < (NCLS + 1) * 64; i += 256) {
    const int c = i >> 6, r = i & 63;
    part[((size_t)g * (NCLS + 1) + c) * NROWS + n0 + r] = cls_lds[i];
  }
#undef FLUSH
#undef CTSTEP
#undef EPI
}

// ---- finalize: sum groups, normalize, clip ----
__global__ __launch_bounds__(256) void k_final(const float* __restrict__ part,
                                               float* __restrict__ out)
{
  const int n = blockIdx.x * 256 + threadIdx.x;   // 8192
  float sc[NCLS];
  #pragma unroll
  for (int c = 0; c < NCLS; ++c) sc[c] = 0.f;
  for (int g = 0; g < GY; ++g) {
    #pragma unroll
    for (int c = 0; c < NCLS; ++c)
      sc[c] += part[((size_t)g * (NCLS + 1) + c) * NROWS + n];
  }
  float tot = 0.f;
  #pragma unroll
  for (int c = 0; c < NCLS; ++c) tot += sc[c];
  const float inv = 1.f / tot;
  #pragma unroll
  for (int c = 0; c < NCLS; ++c)
    out[(size_t)n * NCLS + c] = fminf(fmaxf(sc[c] * inv, 0.f), 1.f);
}

extern "C" void kernel_launch(void* const* d_in, const int* in_sizes, int n_in,
                              void* d_out, int out_size, void* d_ws, size_t ws_size,
                              hipStream_t stream) {
  const float* x   = (const float*)d_in[0];
  const float* xn  = (const float*)d_in[1];
  const int*   yn  = (const int*)d_in[2];
  const float* W0  = (const float*)d_in[3];
  const float* b0  = (const float*)d_in[4];
  const float* g0  = (const float*)d_in[5];
  const float* bt0 = (const float*)d_in[6];
  const float* W1  = (const float*)d_in[7];
  const float* b1  = (const float*)d_in[8];
  const float* g1  = (const float*)d_in[9];
  const float* bt1 = (const float*)d_in[10];
  float* out = (float*)d_out;
  float* ws  = (float*)d_ws;

  float* w0tp = ws + OFF_W0T;
  float* h1p  = ws + OFF_H1;
  float* p1sp = ws + OFF_P1S;
  float* p1qp = ws + OFF_P1Q;
  float* sc0p = ws + OFF_SC0;
  float* sh0p = ws + OFF_SH0;
  float* w1ep = ws + OFF_W1E;
  float* b1ep = ws + OFF_B1E;
  float* h2p  = ws + OFF_H2;
  float* p2sp = ws + OFF_P2S;
  float* p2qp = ws + OFF_P2Q;
  float* sc1p = ws + OFF_SC1;
  float* sh1p = ws + OFF_SH1;
  u16*   qhp  = (u16*)(ws + OFF_QH);
  u16*   qlp  = (u16*)(ws + OFF_QL);
  float* qn2p = ws + OFF_QN2;
  u16*   khp  = (u16*)(ws + OFF_KH);
  u16*   klp  = (u16*)(ws + OFF_KL);
  float* kn2p = ws + OFF_KN2;
  int*   pidxp= (int*)(ws + OFF_PIDX);
  int*   tclsp= (int*)(ws + OFF_TCLS);
  float* partp= ws + OFF_PART;

  k_sort<<<1, 256, 0, stream>>>(yn, pidxp, tclsp);
  k_w0t<<<128, 256, 0, stream>>>(W0, w0tp);
  k_layer1<<<NB1, 128, 0, stream>>>(x, xn, w0tp, b0, h1p, p1sp, p1qp);
  k_red1<<<256, 64, 0, stream>>>(p1sp, p1qp, g0, bt0, sc0p, sh0p);
  k_fold<<<1, 128, 0, stream>>>(W1, b1, sc0p, sh0p, w1ep, b1ep);
  k_layer2<<<NB2, 64, 0, stream>>>(h1p, w1ep, b1ep, h2p, p2sp, p2qp);
  k_red2<<<128, 64, 0, stream>>>(p2sp, p2qp, g1, bt1, sc1p, sh1p);
  k_bn2q<<<NROWS / 4, 256, 0, stream>>>(h2p, sc1p, sh1p, qhp, qlp, qn2p);
  k_bn2k<<<MPAD / 4, 256, 0, stream>>>(h2p, sc1p, sh1p, pidxp, khp, klp, kn2p);
  k_dist<<<dim3(NROWS / 64, GY), 256, 0, stream>>>(qhp, qlp, qn2p, khp, klp, kn2p, tclsp, partp);
  k_final<<<NROWS / 256, 256, 0, stream>>>(partp, out);
}

// Round 3
// 152.568 us; speedup vs baseline: 2.2165x; 1.1884x over previous
//
#include <hip/hip_runtime.h>
#include <math.h>

#define EPSBN 1e-5f

typedef unsigned short u16;
typedef short bf16x8 __attribute__((ext_vector_type(8)));
typedef float f32x4 __attribute__((ext_vector_type(4)));
typedef int i32x4 __attribute__((ext_vector_type(4)));

constexpr int NROWS = 8192;
constexpr int D0 = 256;
constexpr int F1 = 128;
constexpr int F2 = 64;
constexpr int TOT = 2 * NROWS;
constexpr int NCLS = 10;
constexpr int MPAD = 8832;        // 138 tiles of 64
constexpr int NT_PAD = MPAD / 64; // 138
constexpr int GY = 12;

// workspace offsets (floats)
constexpr size_t OFF_W0P = 0;                                   // u16[2*32*1024] = 32768 f
constexpr size_t OFF_H1H = 32768;                               // u16[16384*128] = 1048576 f
constexpr size_t OFF_H1L = OFF_H1H + 1048576;
constexpr size_t OFF_P1S = OFF_H1L + 1048576;                   // 1024*128
constexpr size_t OFF_P1Q = OFF_P1S + 131072;
constexpr size_t OFF_SC0 = OFF_P1Q + 131072;
constexpr size_t OFF_SH0 = OFF_SC0 + 256;
constexpr size_t OFF_W1P = OFF_SH0 + 256;                       // u16[64*512] = 16384 f
constexpr size_t OFF_B1E = OFF_W1P + 16384;
constexpr size_t OFF_H2  = OFF_B1E + 128;                       // 16384*64
constexpr size_t OFF_P2S = OFF_H2 + 1048576;                    // 1024*64
constexpr size_t OFF_P2Q = OFF_P2S + 65536;
constexpr size_t OFF_SC1 = OFF_P2Q + 65536;
constexpr size_t OFF_SH1 = OFF_SC1 + 128;
constexpr size_t OFF_PIDX= OFF_SH1 + 128;                       // int[8832]
constexpr size_t OFF_TCLS= OFF_PIDX + MPAD;                     // int[160]
// overlays: qk features over h1 (dead after layer2)
constexpr size_t OFF_QH  = OFF_H1H;                             // u16[8192*64] = 262144 f
constexpr size_t OFF_QL  = OFF_QH + 262144;
constexpr size_t OFF_QN2 = OFF_QL + 262144;                     // 8192
constexpr size_t OFF_KH  = OFF_QN2 + NROWS;                     // u16[8832*64] = 282624 f
constexpr size_t OFF_KL  = OFF_KH + 282624;
constexpr size_t OFF_KN2 = OFF_KL + 282624;                     // 8832 (ends < OFF_P1S)
// part over h2+p2s+p2q (dead after bn2/red2): 12*11*8192 = 1081344 <= 1179648
constexpr size_t OFF_PART= OFF_H2;

__device__ inline u16 f2bf(float f) {
  unsigned u = __float_as_uint(f);
  unsigned r = (u + 0x7fffu + ((u >> 16) & 1u)) >> 16;
  return (u16)r;
}
__device__ inline float bf2f(u16 h) { return __uint_as_float(((unsigned)h) << 16); }

__device__ inline float tanh_fast(float x) {
  // tanh(x) = 1 - 2/(exp(2x)+1); exp(2x) = exp2(x*2/ln2)
  float e = __builtin_amdgcn_exp2f(x * 2.88539008f);
  return 1.f - 2.f * __builtin_amdgcn_rcpf(e + 1.f);
}

// ---------------- pack W0 into B-fragment order, bf16 hi/lo ----------------
// w0p[arr][kidx=k>>3][j][k&7], arr stride 32768 u16
__global__ void k_w0pack(const float* __restrict__ w0, u16* __restrict__ w0p) {
  int idx = blockIdx.x * 256 + threadIdx.x;   // 32768
  int j = idx >> 8, t = idx & 255;
  float v = w0[idx];
  u16 hi = f2bf(v);
  u16 lo = f2bf(v - bf2f(hi));
  w0p[(t >> 3) * 1024 + j * 8 + (t & 7)] = hi;
  w0p[32768 + (t >> 3) * 1024 + j * 8 + (t & 7)] = lo;
}

// ---------------- layer 1: MFMA, split-bf16 3-pass ----------------
__global__ __launch_bounds__(256) void k_layer1(
    const float* __restrict__ x, const float* __restrict__ xn,
    const u16* __restrict__ w0p, const float* __restrict__ b0,
    u16* __restrict__ h1h, u16* __restrict__ h1l,
    float* __restrict__ p1s, float* __restrict__ p1q)
{
  const int tid = threadIdx.x;
  const int w = tid >> 6, l = tid & 63;
  const int l15 = l & 15, l4 = l >> 4;
  const int blk = blockIdx.x;                 // 512
  const int rowHalf = w & 1, colHalf = w >> 1;
  const int r0 = blk * 32 + 16 * rowHalf;
  const int c0 = 64 * colHalf;
  const float* src = (blk < 256) ? (x + (size_t)blk * 32 * 256)
                                 : (xn + (size_t)(blk - 256) * 32 * 256);
  const float* xrow = src + (size_t)(16 * rowHalf + l15) * 256;

  f32x4 acc[4];
  #pragma unroll
  for (int ct = 0; ct < 4; ++ct) acc[ct] = (f32x4){0.f, 0.f, 0.f, 0.f};

  #pragma unroll
  for (int ks = 0; ks < 8; ++ks) {
    const float* xp = xrow + ks * 32 + l4 * 8;
    f32x4 a0 = *(const f32x4*)xp;
    f32x4 a1 = *(const f32x4*)(xp + 4);
    bf16x8 ah, al_;
    #pragma unroll
    for (int i = 0; i < 4; ++i) {
      u16 h = f2bf(a0[i]); ah[i] = (short)h; al_[i] = (short)f2bf(a0[i] - bf2f(h));
    }
    #pragma unroll
    for (int i = 0; i < 4; ++i) {
      u16 h = f2bf(a1[i]); ah[4 + i] = (short)h; al_[4 + i] = (short)f2bf(a1[i] - bf2f(h));
    }
    const u16* bbase = w0p + (size_t)(ks * 4 + l4) * 1024;
    #pragma unroll
    for (int ct = 0; ct < 4; ++ct) {
      const int col = c0 + 16 * ct + l15;
      bf16x8 bh = *(const bf16x8*)(bbase + col * 8);
      bf16x8 bl = *(const bf16x8*)(bbase + 32768 + col * 8);
      acc[ct] = __builtin_amdgcn_mfma_f32_16x16x32_bf16(ah, bh, acc[ct], 0, 0, 0);
      acc[ct] = __builtin_amdgcn_mfma_f32_16x16x32_bf16(ah, bl, acc[ct], 0, 0, 0);
      acc[ct] = __builtin_amdgcn_mfma_f32_16x16x32_bf16(al_, bh, acc[ct], 0, 0, 0);
    }
  }

  #pragma unroll
  for (int ct = 0; ct < 4; ++ct) {
    const int col = c0 + 16 * ct + l15;
    const float bj = b0[col];
    float s = 0.f, q = 0.f;
    #pragma unroll
    for (int r = 0; r < 4; ++r) {
      float v = tanh_fast(acc[ct][r] + bj);
      const int row = r0 + 4 * l4 + r;
      u16 hi = f2bf(v);
      h1h[(size_t)row * 128 + col] = hi;
      h1l[(size_t)row * 128 + col] = f2bf(v - bf2f(hi));
      s += v; q += v * v;
    }
    s += __shfl_xor(s, 16); s += __shfl_xor(s, 32);
    q += __shfl_xor(q, 16); q += __shfl_xor(q, 32);
    if (l < 16) {
      p1s[(size_t)(blk * 2 + rowHalf) * 128 + col] = s;
      p1q[(size_t)(blk * 2 + rowHalf) * 128 + col] = q;
    }
  }
}

__global__ __launch_bounds__(64) void k_red1(
    const float* __restrict__ p1s, const float* __restrict__ p1q,
    const float* __restrict__ g0, const float* __restrict__ bt0,
    float* __restrict__ sc0, float* __restrict__ sh0)
{
  const int b = blockIdx.x >> 7;
  const int j = blockIdx.x & 127;
  const int t = threadIdx.x;
  float s = 0.f, q = 0.f;
  for (int i = t; i < 512; i += 64) {
    s += p1s[(size_t)(b * 512 + i) * 128 + j];
    q += p1q[(size_t)(b * 512 + i) * 128 + j];
  }
  #pragma unroll
  for (int off = 32; off; off >>= 1) { s += __shfl_xor(s, off); q += __shfl_xor(q, off); }
  if (t == 0) {
    float m = s / (float)NROWS;
    float v = q / (float)NROWS - m * m;
    float sc = g0[j] * rsqrtf(v + EPSBN);
    sc0[b * 128 + j] = sc;
    sh0[b * 128 + j] = bt0[j] - m * sc;
  }
}

// ---- fold BN1 into W1; emit packed bf16 hi/lo frags + eff bias ----
__global__ __launch_bounds__(128) void k_fold(
    const float* __restrict__ w1, const float* __restrict__ b1,
    const float* __restrict__ sc0, const float* __restrict__ sh0,
    u16* __restrict__ w1p, float* __restrict__ b1e)
{
  const int tid = threadIdx.x;
  const int b = tid >> 6, o = tid & 63;
  float acc = 0.f;
  for (int j = 0; j < 128; ++j) {
    float w = w1[o * 128 + j];
    float ws = w * sc0[b * 128 + j];
    acc += w * sh0[b * 128 + j];
    u16 hi = f2bf(ws);
    u16 lo = f2bf(ws - bf2f(hi));
    w1p[((size_t)(b * 2 + 0) * 16 + (j >> 3)) * 512 + o * 8 + (j & 7)] = hi;
    w1p[((size_t)(b * 2 + 1) * 16 + (j >> 3)) * 512 + o * 8 + (j & 7)] = lo;
  }
  b1e[b * 64 + o] = b1[o] + acc;
}

// ---------------- layer 2: MFMA, split-bf16 3-pass ----------------
__global__ __launch_bounds__(256) void k_layer2(
    const u16* __restrict__ h1h, const u16* __restrict__ h1l,
    const u16* __restrict__ w1p, const float* __restrict__ b1e,
    float* __restrict__ h2, float* __restrict__ p2s, float* __restrict__ p2q)
{
  const int tid = threadIdx.x;
  const int w = tid >> 6, l = tid & 63;
  const int l15 = l & 15, l4 = l >> 4;
  const int blk = blockIdx.x;                 // 512
  const int rowHalf = w & 1, colHalf = w >> 1;
  const int r0 = blk * 32 + 16 * rowHalf;
  const int c0 = 32 * colHalf;
  const int b = blk >> 8;
  const u16* arow_h = h1h + (size_t)(r0 + l15) * 128;
  const u16* arow_l = h1l + (size_t)(r0 + l15) * 128;

  f32x4 acc[2];
  acc[0] = (f32x4){0.f, 0.f, 0.f, 0.f};
  acc[1] = (f32x4){0.f, 0.f, 0.f, 0.f};

  #pragma unroll
  for (int ks = 0; ks < 4; ++ks) {
    bf16x8 ah = *(const bf16x8*)(arow_h + ks * 32 + l4 * 8);
    bf16x8 al_ = *(const bf16x8*)(arow_l + ks * 32 + l4 * 8);
    const u16* bb = w1p + ((size_t)(b * 2) * 16 + ks * 4 + l4) * 512;
    #pragma unroll
    for (int ct = 0; ct < 2; ++ct) {
      const int col = c0 + 16 * ct + l15;
      bf16x8 bh = *(const bf16x8*)(bb + col * 8);
      bf16x8 bl = *(const bf16x8*)(bb + 8192 + col * 8);
      acc[ct] = __builtin_amdgcn_mfma_f32_16x16x32_bf16(ah, bh, acc[ct], 0, 0, 0);
      acc[ct] = __builtin_amdgcn_mfma_f32_16x16x32_bf16(ah, bl, acc[ct], 0, 0, 0);
      acc[ct] = __builtin_amdgcn_mfma_f32_16x16x32_bf16(al_, bh, acc[ct], 0, 0, 0);
    }
  }

  #pragma unroll
  for (int ct = 0; ct < 2; ++ct) {
    const int col = c0 + 16 * ct + l15;
    const float bj = b1e[b * 64 + col];
    float s = 0.f, q = 0.f;
    #pragma unroll
    for (int r = 0; r < 4; ++r) {
      float v = tanh_fast(acc[ct][r] + bj);
      const int row = r0 + 4 * l4 + r;
      h2[(size_t)row * 64 + col] = v;
      s += v; q += v * v;
    }
    s += __shfl_xor(s, 16); s += __shfl_xor(s, 32);
    q += __shfl_xor(q, 16); q += __shfl_xor(q, 32);
    if (l < 16) {
      p2s[(size_t)(blk * 2 + rowHalf) * 64 + col] = s;
      p2q[(size_t)(blk * 2 + rowHalf) * 64 + col] = q;
    }
  }
}

__global__ __launch_bounds__(64) void k_red2(
    const float* __restrict__ p2s, const float* __restrict__ p2q,
    const float* __restrict__ g1, const float* __restrict__ bt1,
    float* __restrict__ sc1, float* __restrict__ sh1)
{
  const int b = blockIdx.x >> 6;
  const int o = blockIdx.x & 63;
  const int t = threadIdx.x;
  float s = 0.f, q = 0.f;
  for (int i = t; i < 512; i += 64) {
    s += p2s[(size_t)(b * 512 + i) * 64 + o];
    q += p2q[(size_t)(b * 512 + i) * 64 + o];
  }
  #pragma unroll
  for (int off = 32; off; off >>= 1) { s += __shfl_xor(s, off); q += __shfl_xor(q, off); }
  if (t == 0) {
    float m = s / (float)NROWS;
    float v = q / (float)NROWS - m * m;
    float sc = g1[o] * rsqrtf(v + EPSBN);
    sc1[b * 64 + o] = sc;
    sh1[b * 64 + o] = bt1[o] - m * sc;
  }
}

// ---------------- stable counting sort of K rows by class ----------------
__global__ __launch_bounds__(256) void k_sort(const int* __restrict__ yn,
                                              int* __restrict__ pidx, int* __restrict__ tcls)
{
  __shared__ int cnt[256][NCLS];
  __shared__ int wtot[4][NCLS];
  __shared__ int pstart[NCLS + 1];
  const int t = threadIdx.x;
  const int lane = t & 63, w = t >> 6;
  #pragma unroll
  for (int c = 0; c < NCLS; ++c) cnt[t][c] = 0;
  for (int i = t; i < MPAD; i += 256) pidx[i] = -1;
  const int base = t * 32;
  for (int i = 0; i < 32; ++i) cnt[t][yn[base + i]]++;
  __syncthreads();
  #pragma unroll
  for (int c = 0; c < NCLS; ++c) {
    int x = cnt[t][c];
    int inc = x;
    #pragma unroll
    for (int d = 1; d < 64; d <<= 1) { int y = __shfl_up(inc, d); if (lane >= d) inc += y; }
    if (lane == 63) wtot[w][c] = inc;
    cnt[t][c] = inc - x;
  }
  __syncthreads();
  if (t == 0) {
    int run = 0;
    #pragma unroll
    for (int c = 0; c < NCLS; ++c) {
      int tot = wtot[0][c] + wtot[1][c] + wtot[2][c] + wtot[3][c];
      pstart[c] = run;
      int ntile = (tot + 63) >> 6;
      for (int tt = 0; tt < ntile; ++tt) tcls[(run >> 6) + tt] = c;
      run += ntile << 6;
    }
    pstart[NCLS] = run;
    for (int tt = run >> 6; tt < NT_PAD; ++tt) tcls[tt] = NCLS;
  }
  __syncthreads();
  #pragma unroll
  for (int c = 0; c < NCLS; ++c) {
    int add = pstart[c];
    for (int w2 = 0; w2 < 4; ++w2) if (w2 < w) add += wtot[w2][c];
    cnt[t][c] += add;
  }
  __syncthreads();
  for (int i = 0; i < 32; ++i) {
    int idx = base + i;
    int c = yn[idx];
    pidx[cnt[t][c]++] = idx;
  }
}

// ---------------- BN2 + bf16 split (q and permuted/padded k sides) ----------------
__global__ __launch_bounds__(256) void k_bn2(
    const float* __restrict__ h2, const float* __restrict__ sc1, const float* __restrict__ sh1,
    const int* __restrict__ pidx,
    u16* __restrict__ qh, u16* __restrict__ ql, float* __restrict__ qn2,
    u16* __restrict__ kh, u16* __restrict__ kl, float* __restrict__ kn2)
{
  const int tid = threadIdx.x;
  const int r = tid >> 6, o = tid & 63;
  if (blockIdx.x < 2048) {
    const int row = blockIdx.x * 4 + r;
    float v = sc1[o] * h2[(size_t)row * 64 + o] + sh1[o];
    u16 hi = f2bf(v);
    qh[(size_t)row * 64 + o] = hi;
    ql[(size_t)row * 64 + o] = f2bf(v - bf2f(hi));
    float sq = v * v;
    #pragma unroll
    for (int off = 32; off; off >>= 1) sq += __shfl_xor(sq, off);
    if (o == 0) qn2[row] = sq;
  } else {
    const int row = (blockIdx.x - 2048) * 4 + r;   // 0..8831
    const int src = pidx[row];
    float v = 0.f;
    if (src >= 0) v = sc1[64 + o] * h2[(size_t)(NROWS + src) * 64 + o] + sh1[64 + o];
    u16 hi = f2bf(v);
    kh[(size_t)row * 64 + o] = hi;
    kl[(size_t)row * 64 + o] = f2bf(v - bf2f(hi));
    float sq = v * v;
    #pragma unroll
    for (int off = 32; off; off >>= 1) sq += __shfl_xor(sq, off);
    if (o == 0) kn2[row] = (src >= 0) ? sq : 1e30f;
  }
}

// ---------------- MFMA cdist + fast exp + per-class accumulation ----------------
__global__ __launch_bounds__(256) void k_dist(
    const u16* __restrict__ qh, const u16* __restrict__ ql, const float* __restrict__ qn2,
    const u16* __restrict__ kh, const u16* __restrict__ kl, const float* __restrict__ kn2,
    const int* __restrict__ tcls, float* __restrict__ part)
{
  __shared__ u16 bs[64 * 128];
  __shared__ float cls_lds[(NCLS + 1) * 64];
  const int tid = threadIdx.x;
  const int l = tid & 63, w = tid >> 6;
  const int n0 = blockIdx.x * 64;
  const int g = blockIdx.y;
  const int t0 = g * 12;
  const int t1 = (t0 + 12 < NT_PAD) ? (t0 + 12) : NT_PAD;

  for (int i = tid; i < (NCLS + 1) * 64; i += 256) cls_lds[i] = 0.f;

  const int l15 = l & 15, l4 = l >> 4;
  const int arow = n0 + 16 * w + l15;
  const bf16x8 aH0 = *(const bf16x8*)(qh + (size_t)arow * 64 + l4 * 8);
  const bf16x8 aH1 = *(const bf16x8*)(qh + (size_t)arow * 64 + 32 + l4 * 8);
  const bf16x8 aL0 = *(const bf16x8*)(ql + (size_t)arow * 64 + l4 * 8);
  const bf16x8 aL1 = *(const bf16x8*)(ql + (size_t)arow * 64 + 32 + l4 * 8);
  const f32x4 qn = *(const f32x4*)(qn2 + n0 + 16 * w + l4 * 4);

  const ushort* arrp = ((tid >> 3) & 1) ? kl : kh;
  const int cp8 = (tid & 7) * 8;
  const int colb = tid >> 4;
  const int slot = ((tid >> 3) & 1) * 8 + ((tid & 7) ^ (colb & 7));
  char* dstb = (char*)bs + colb * 256 + slot * 16;

  const int P = l15 * 256 + ((l4 ^ (l & 7)) << 4);
  const char* bb = (const char*)bs;

  i32x4 st0, st1, st2, st3;
  {
    const int m0 = t0 * 64;
    st0 = *(const i32x4*)(arrp + (size_t)(m0 + colb) * 64 + cp8);
    st1 = *(const i32x4*)(arrp + (size_t)(m0 + 16 + colb) * 64 + cp8);
    st2 = *(const i32x4*)(arrp + (size_t)(m0 + 32 + colb) * 64 + cp8);
    st3 = *(const i32x4*)(arrp + (size_t)(m0 + 48 + colb) * 64 + cp8);
  }

  float run0 = 0.f, run1 = 0.f, run2 = 0.f, run3 = 0.f;
  int ccur = tcls[t0];

#define FLUSH(CC) { \
    run0 += __shfl_xor(run0, 1); run0 += __shfl_xor(run0, 2); run0 += __shfl_xor(run0, 4); run0 += __shfl_xor(run0, 8); \
    run1 += __shfl_xor(run1, 1); run1 += __shfl_xor(run1, 2); run1 += __shfl_xor(run1, 4); run1 += __shfl_xor(run1, 8); \
    run2 += __shfl_xor(run2, 1); run2 += __shfl_xor(run2, 2); run2 += __shfl_xor(run2, 4); run2 += __shfl_xor(run2, 8); \
    run3 += __shfl_xor(run3, 1); run3 += __shfl_xor(run3, 2); run3 += __shfl_xor(run3, 4); run3 += __shfl_xor(run3, 8); \
    if (l15 == 0) { \
      float* cl = cls_lds + (CC) * 64 + 16 * w + l4 * 4; \
      cl[0] += run0; cl[1] += run1; cl[2] += run2; cl[3] += run3; \
    } \
    run0 = run1 = run2 = run3 = 0.f; \
  }

#define CTSTEP(CT, ACC) { \
    const char* pp = bb + (CT) * 4096; \
    bf16x8 bh0 = *(const bf16x8*)(pp + P); \
    bf16x8 bh1 = *(const bf16x8*)(pp + (P ^ 64)); \
    bf16x8 bl0 = *(const bf16x8*)(pp + (P ^ 128)); \
    bf16x8 bl1 = *(const bf16x8*)(pp + (P ^ 192)); \
    ACC = __builtin_amdgcn_mfma_f32_16x16x32_bf16(aH0, bh0, ACC, 0, 0, 0); \
    ACC = __builtin_amdgcn_mfma_f32_16x16x32_bf16(aH1, bh1, ACC, 0, 0, 0); \
    ACC = __builtin_amdgcn_mfma_f32_16x16x32_bf16(aH0, bl0, ACC, 0, 0, 0); \
    ACC = __builtin_amdgcn_mfma_f32_16x16x32_bf16(aH1, bl1, ACC, 0, 0, 0); \
    ACC = __builtin_amdgcn_mfma_f32_16x16x32_bf16(aL0, bh0, ACC, 0, 0, 0); \
    ACC = __builtin_amdgcn_mfma_f32_16x16x32_bf16(aL1, bh1, ACC, 0, 0, 0); \
  }

#define EPI(ACC, KV) { \
    float d2, s_, u; \
    d2 = fmaxf(fmaf(-2.f, ACC[0], qn[0] + (KV)), 1e-12f); \
    s_ = __builtin_amdgcn_sqrtf(d2); \
    u = __builtin_amdgcn_exp2f(s_ * -1.44269504f); run0 += u; \
    d2 = fmaxf(fmaf(-2.f, ACC[1], qn[1] + (KV)), 1e-12f); \
    s_ = __builtin_amdgcn_sqrtf(d2); \
    u = __builtin_amdgcn_exp2f(s_ * -1.44269504f); run1 += u; \
    d2 = fmaxf(fmaf(-2.f, ACC[2], qn[2] + (KV)), 1e-12f); \
    s_ = __builtin_amdgcn_sqrtf(d2); \
    u = __builtin_amdgcn_exp2f(s_ * -1.44269504f); run2 += u; \
    d2 = fmaxf(fmaf(-2.f, ACC[3], qn[3] + (KV)), 1e-12f); \
    s_ = __builtin_amdgcn_sqrtf(d2); \
    u = __builtin_amdgcn_exp2f(s_ * -1.44269504f); run3 += u; \
  }

  for (int t = t0; t < t1; ++t) {
    const int m0 = t * 64;
    __syncthreads();
    *(i32x4*)(dstb)         = st0;
    *(i32x4*)(dstb + 4096)  = st1;
    *(i32x4*)(dstb + 8192)  = st2;
    *(i32x4*)(dstb + 12288) = st3;
    __syncthreads();
    if (t + 1 < t1) {
      const int m1 = m0 + 64;
      st0 = *(const i32x4*)(arrp + (size_t)(m1 + colb) * 64 + cp8);
      st1 = *(const i32x4*)(arrp + (size_t)(m1 + 16 + colb) * 64 + cp8);
      st2 = *(const i32x4*)(arrp + (size_t)(m1 + 32 + colb) * 64 + cp8);
      st3 = *(const i32x4*)(arrp + (size_t)(m1 + 48 + colb) * 64 + cp8);
    }
    const float kv0 = kn2[m0 + l15];
    const float kv1 = kn2[m0 + 16 + l15];
    const float kv2 = kn2[m0 + 32 + l15];
    const float kv3 = kn2[m0 + 48 + l15];
    const int c = tcls[t];
    if (c != ccur) { FLUSH(ccur); ccur = c; }

    f32x4 acc0 = {0.f, 0.f, 0.f, 0.f};
    f32x4 acc1 = {0.f, 0.f, 0.f, 0.f};
    f32x4 acc2 = {0.f, 0.f, 0.f, 0.f};
    f32x4 acc3 = {0.f, 0.f, 0.f, 0.f};
    CTSTEP(0, acc0)
    CTSTEP(1, acc1)
    CTSTEP(2, acc2)
    CTSTEP(3, acc3)
    EPI(acc0, kv0)
    EPI(acc1, kv1)
    EPI(acc2, kv2)
    EPI(acc3, kv3)
  }
  FLUSH(ccur);
  __syncthreads();

  for (int i = tid; i < (NCLS + 1) * 64; i += 256) {
    const int c = i >> 6, r = i & 63;
    part[((size_t)g * (NCLS + 1) + c) * NROWS + n0 + r] = cls_lds[i];
  }
#undef FLUSH
#undef CTSTEP
#undef EPI
}

// ---- finalize ----
__global__ __launch_bounds__(256) void k_final(const float* __restrict__ part,
                                               float* __restrict__ out)
{
  const int n = blockIdx.x * 256 + threadIdx.x;
  float sc[NCLS];
  #pragma unroll
  for (int c = 0; c < NCLS; ++c) sc[c] = 0.f;
  for (int g = 0; g < GY; ++g) {
    #pragma unroll
    for (int c = 0; c < NCLS; ++c)
      sc[c] += part[((size_t)g * (NCLS + 1) + c) * NROWS + n];
  }
  float tot = 0.f;
  #pragma unroll
  for (int c = 0; c < NCLS; ++c) tot += sc[c];
  const float inv = 1.f / tot;
  #pragma unroll
  for (int c = 0; c < NCLS; ++c)
    out[(size_t)n * NCLS + c] = fminf(fmaxf(sc[c] * inv, 0.f), 1.f);
}

extern "C" void kernel_launch(void* const* d_in, const int* in_sizes, int n_in,
                              void* d_out, int out_size, void* d_ws, size_t ws_size,
                              hipStream_t stream) {
  const float* x   = (const float*)d_in[0];
  const float* xn  = (const float*)d_in[1];
  const int*   yn  = (const int*)d_in[2];
  const float* W0  = (const float*)d_in[3];
  const float* b0  = (const float*)d_in[4];
  const float* g0  = (const float*)d_in[5];
  const float* bt0 = (const float*)d_in[6];
  const float* W1  = (const float*)d_in[7];
  const float* b1  = (const float*)d_in[8];
  const float* g1  = (const float*)d_in[9];
  const float* bt1 = (const float*)d_in[10];
  float* out = (float*)d_out;
  float* ws  = (float*)d_ws;

  u16*   w0pp = (u16*)(ws + OFF_W0P);
  u16*   h1hp = (u16*)(ws + OFF_H1H);
  u16*   h1lp = (u16*)(ws + OFF_H1L);
  float* p1sp = ws + OFF_P1S;
  float* p1qp = ws + OFF_P1Q;
  float* sc0p = ws + OFF_SC0;
  float* sh0p = ws + OFF_SH0;
  u16*   w1pp = (u16*)(ws + OFF_W1P);
  float* b1ep = ws + OFF_B1E;
  float* h2p  = ws + OFF_H2;
  float* p2sp = ws + OFF_P2S;
  float* p2qp = ws + OFF_P2Q;
  float* sc1p = ws + OFF_SC1;
  float* sh1p = ws + OFF_SH1;
  int*   pidxp= (int*)(ws + OFF_PIDX);
  int*   tclsp= (int*)(ws + OFF_TCLS);
  u16*   qhp  = (u16*)(ws + OFF_QH);
  u16*   qlp  = (u16*)(ws + OFF_QL);
  float* qn2p = ws + OFF_QN2;
  u16*   khp  = (u16*)(ws + OFF_KH);
  u16*   klp  = (u16*)(ws + OFF_KL);
  float* kn2p = ws + OFF_KN2;
  float* partp= ws + OFF_PART;

  k_sort<<<1, 256, 0, stream>>>(yn, pidxp, tclsp);
  k_w0pack<<<128, 256, 0, stream>>>(W0, w0pp);
  k_layer1<<<512, 256, 0, stream>>>(x, xn, w0pp, b0, h1hp, h1lp, p1sp, p1qp);
  k_red1<<<256, 64, 0, stream>>>(p1sp, p1qp, g0, bt0, sc0p, sh0p);
  k_fold<<<1, 128, 0, stream>>>(W1, b1, sc0p, sh0p, w1pp, b1ep);
  k_layer2<<<512, 256, 0, stream>>>(h1hp, h1lp, w1pp, b1ep, h2p, p2sp, p2qp);
  k_red2<<<128, 64, 0, stream>>>(p2sp, p2qp, g1, bt1, sc1p, sh1p);
  k_bn2<<<2048 + MPAD / 4, 256, 0, stream>>>(h2p, sc1p, sh1p, pidxp,
                                             qhp, qlp, qn2p, khp, klp, kn2p);
  k_dist<<<dim3(128, GY), 256, 0, stream>>>(qhp, qlp, qn2p, khp, klp, kn2p, tclsp, partp);
  k_final<<<32, 256, 0, stream>>>(partp, out);
}

// Round 4
// 137.431 us; speedup vs baseline: 2.4606x; 1.1101x over previous
//
#include <hip/hip_runtime.h>
#include <math.h>

#define EPSBN 1e-5f
#define AADD(p, v) __hip_atomic_fetch_add((p), (v), __ATOMIC_RELAXED, __HIP_MEMORY_SCOPE_AGENT)

typedef unsigned short u16;
typedef short bf16x8 __attribute__((ext_vector_type(8)));
typedef float f32x4 __attribute__((ext_vector_type(4)));
typedef float f32x16 __attribute__((ext_vector_type(16)));
typedef int i32x4 __attribute__((ext_vector_type(4)));

constexpr int NROWS = 8192;
constexpr int NCLS = 10;
constexpr int MPAD = 8832;        // 138 tiles of 64
constexpr int NT_PAD = 138;
constexpr int GY = 6;             // 6 groups x 23 tiles = 138 exactly
constexpr int TPG = 23;
constexpr float SCL  = 2.0813689810056077f;   // (log2 e)^2
constexpr float SCL2 = -4.1627379620112154f;  // -2*(log2 e)^2

// workspace offsets (floats)
constexpr size_t OFF_W0P = 0;                      // u16[65536]
constexpr size_t OFF_H1H = 32768;                  // u16[16384*128]
constexpr size_t OFF_H1L = OFF_H1H + 1048576;
constexpr size_t OFF_SUM = OFF_H1L + 1048576;      // 768 floats: s1[256],q1[256],s2[128],q2[128]
constexpr size_t OFF_W1P = OFF_SUM + 768;          // u16[32768]
constexpr size_t OFF_B1E = OFF_W1P + 16384;        // 128
constexpr size_t OFF_H2  = OFF_B1E + 128;          // 16384*64 floats
constexpr size_t OFF_PIDX = OFF_H2 + 1048576;      // int[8832]
constexpr size_t OFF_TCLS = OFF_PIDX + MPAD;       // int[144]
// overlays over h1 (dead after layer2)
constexpr size_t OFF_QH  = OFF_H1H;                // u16[8192*64]
constexpr size_t OFF_QL  = OFF_QH + 262144;
constexpr size_t OFF_QN2 = OFF_QL + 262144;        // 8192 f
constexpr size_t OFF_KH  = OFF_QN2 + NROWS;        // u16[8832*64]
constexpr size_t OFF_KL  = OFF_KH + 282624;
constexpr size_t OFF_KN2 = OFF_KL + 282624;        // 8832 f (ends 1139328 < 2129920 ok)
// part over h2 (dead after bn2): 6*11*8192 = 540672 <= 1048576
constexpr size_t OFF_PART = OFF_H2;

__device__ inline u16 f2bf(float f) {
  unsigned u = __float_as_uint(f);
  unsigned r = (u + 0x7fffu + ((u >> 16) & 1u)) >> 16;
  return (u16)r;
}
__device__ inline float bf2f(u16 h) { return __uint_as_float(((unsigned)h) << 16); }

__device__ inline float tanh_fast(float x) {
  float e = __builtin_amdgcn_exp2f(x * 2.88539008f);
  return 1.f - 2.f * __builtin_amdgcn_rcpf(e + 1.f);
}

// ---------------- prep: W0 pack (blocks 0-127) + sort + zero sums (block 128) --------
__global__ __launch_bounds__(256) void k_prep(
    const float* __restrict__ w0, const int* __restrict__ yn,
    u16* __restrict__ w0p, int* __restrict__ pidx, int* __restrict__ tcls,
    float* __restrict__ sums)
{
  if (blockIdx.x < 128) {
    int idx = blockIdx.x * 256 + threadIdx.x;   // 32768
    int t = idx & 255;
    float v = w0[idx];
    u16 hi = f2bf(v);
    u16 lo = f2bf(v - bf2f(hi));
    int j = idx >> 8;
    w0p[(t >> 3) * 1024 + j * 8 + (t & 7)] = hi;
    w0p[32768 + (t >> 3) * 1024 + j * 8 + (t & 7)] = lo;
    return;
  }
  // ---- block 128: zero accumulators + counting sort (non-stable, coalesced) ----
  __shared__ int cnt[256][NCLS];
  __shared__ int wtot[4][NCLS];
  __shared__ int pstart[NCLS + 1];
  const int t = threadIdx.x;
  const int lane = t & 63, wv = t >> 6;
  sums[t] = 0.f; sums[t + 256] = 0.f; sums[t + 512] = 0.f;
  #pragma unroll
  for (int c = 0; c < NCLS; ++c) cnt[t][c] = 0;
  for (int i = t; i < MPAD; i += 256) pidx[i] = -1;
  for (int i = t; i < NROWS; i += 256) cnt[t][yn[i]]++;
  __syncthreads();
  #pragma unroll
  for (int c = 0; c < NCLS; ++c) {
    int x = cnt[t][c];
    int inc = x;
    #pragma unroll
    for (int d = 1; d < 64; d <<= 1) { int y = __shfl_up(inc, d); if (lane >= d) inc += y; }
    if (lane == 63) wtot[wv][c] = inc;
    cnt[t][c] = inc - x;
  }
  __syncthreads();
  if (t == 0) {
    int run = 0;
    #pragma unroll
    for (int c = 0; c < NCLS; ++c) {
      int tot = wtot[0][c] + wtot[1][c] + wtot[2][c] + wtot[3][c];
      pstart[c] = run;
      int ntile = (tot + 63) >> 6;
      for (int tt = 0; tt < ntile; ++tt) tcls[(run >> 6) + tt] = c;
      run += ntile << 6;
    }
    pstart[NCLS] = run;
    for (int tt = run >> 6; tt < NT_PAD; ++tt) tcls[tt] = NCLS;
  }
  __syncthreads();
  #pragma unroll
  for (int c = 0; c < NCLS; ++c) {
    int add = pstart[c];
    for (int w2 = 0; w2 < 4; ++w2) if (w2 < wv) add += wtot[w2][c];
    cnt[t][c] += add;
  }
  __syncthreads();
  for (int i = t; i < NROWS; i += 256) {
    int c = yn[i];
    pidx[cnt[t][c]++] = i;
  }
}

// ---------------- layer 1: MFMA, split-bf16 3-pass, atomic BN stats ----------------
__global__ __launch_bounds__(256) void k_layer1(
    const float* __restrict__ x, const float* __restrict__ xn,
    const u16* __restrict__ w0p, const float* __restrict__ b0,
    u16* __restrict__ h1h, u16* __restrict__ h1l, float* __restrict__ sums)
{
  const int tid = threadIdx.x;
  const int w = tid >> 6, l = tid & 63;
  const int l15 = l & 15, l4 = l >> 4;
  const int blk = blockIdx.x;                 // 512
  const int rowHalf = w & 1, colHalf = w >> 1;
  const int r0 = blk * 32 + 16 * rowHalf;
  const int c0 = 64 * colHalf;
  const int b = (blk < 256) ? 0 : 1;
  const float* src = (blk < 256) ? (x + (size_t)blk * 32 * 256)
                                 : (xn + (size_t)(blk - 256) * 32 * 256);
  const float* xrow = src + (size_t)(16 * rowHalf + l15) * 256;

  f32x4 acc[4];
  #pragma unroll
  for (int ct = 0; ct < 4; ++ct) acc[ct] = (f32x4){0.f, 0.f, 0.f, 0.f};

  #pragma unroll
  for (int ks = 0; ks < 8; ++ks) {
    const float* xp = xrow + ks * 32 + l4 * 8;
    f32x4 a0 = *(const f32x4*)xp;
    f32x4 a1 = *(const f32x4*)(xp + 4);
    bf16x8 ah, al_;
    #pragma unroll
    for (int i = 0; i < 4; ++i) {
      u16 h = f2bf(a0[i]); ah[i] = (short)h; al_[i] = (short)f2bf(a0[i] - bf2f(h));
    }
    #pragma unroll
    for (int i = 0; i < 4; ++i) {
      u16 h = f2bf(a1[i]); ah[4 + i] = (short)h; al_[4 + i] = (short)f2bf(a1[i] - bf2f(h));
    }
    const u16* bbase = w0p + (size_t)(ks * 4 + l4) * 1024;
    #pragma unroll
    for (int ct = 0; ct < 4; ++ct) {
      const int col = c0 + 16 * ct + l15;
      bf16x8 bh = *(const bf16x8*)(bbase + col * 8);
      bf16x8 bl = *(const bf16x8*)(bbase + 32768 + col * 8);
      acc[ct] = __builtin_amdgcn_mfma_f32_16x16x32_bf16(ah, bh, acc[ct], 0, 0, 0);
      acc[ct] = __builtin_amdgcn_mfma_f32_16x16x32_bf16(ah, bl, acc[ct], 0, 0, 0);
      acc[ct] = __builtin_amdgcn_mfma_f32_16x16x32_bf16(al_, bh, acc[ct], 0, 0, 0);
    }
  }

  #pragma unroll
  for (int ct = 0; ct < 4; ++ct) {
    const int col = c0 + 16 * ct + l15;
    const float bj = b0[col];
    float s = 0.f, q = 0.f;
    #pragma unroll
    for (int r = 0; r < 4; ++r) {
      float v = tanh_fast(acc[ct][r] + bj);
      const int row = r0 + 4 * l4 + r;
      u16 hi = f2bf(v);
      h1h[(size_t)row * 128 + col] = hi;
      h1l[(size_t)row * 128 + col] = f2bf(v - bf2f(hi));
      s += v; q += v * v;
    }
    s += __shfl_xor(s, 16); s += __shfl_xor(s, 32);
    q += __shfl_xor(q, 16); q += __shfl_xor(q, 32);
    if (l < 16) {
      AADD(&sums[b * 128 + col], s);
      AADD(&sums[256 + b * 128 + col], q);
    }
  }
}

// ---- parallel fold: BN1 scale/shift from sums -> packed W1eff + eff bias ----
__global__ __launch_bounds__(128) void k_foldp(
    const float* __restrict__ w1, const float* __restrict__ b1,
    const float* __restrict__ g0, const float* __restrict__ bt0,
    const float* __restrict__ sums, u16* __restrict__ w1p, float* __restrict__ b1e)
{
  const int o = blockIdx.x;          // 64
  const int j = threadIdx.x;         // 128
  __shared__ float red[2][2];
  const float w = w1[o * 128 + j];
  #pragma unroll
  for (int b = 0; b < 2; ++b) {
    float s = sums[b * 128 + j], q = sums[256 + b * 128 + j];
    float m = s * (1.f / 8192.f);
    float v = q * (1.f / 8192.f) - m * m;
    float sc = g0[j] * rsqrtf(v + EPSBN);
    float sh = bt0[j] - m * sc;
    float wsc = w * sc;
    u16 hi = f2bf(wsc);
    u16 lo = f2bf(wsc - bf2f(hi));
    w1p[((size_t)(b * 2 + 0) * 16 + (j >> 3)) * 512 + o * 8 + (j & 7)] = hi;
    w1p[((size_t)(b * 2 + 1) * 16 + (j >> 3)) * 512 + o * 8 + (j & 7)] = lo;
    float a = w * sh;
    #pragma unroll
    for (int off = 32; off; off >>= 1) a += __shfl_xor(a, off);
    if ((j & 63) == 0) red[j >> 6][b] = a;
  }
  __syncthreads();
  if (j < 2) b1e[j * 64 + o] = b1[o] + red[0][j] + red[1][j];
}

// ---------------- layer 2: MFMA, split-bf16 3-pass, atomic BN stats ----------------
__global__ __launch_bounds__(256) void k_layer2(
    const u16* __restrict__ h1h, const u16* __restrict__ h1l,
    const u16* __restrict__ w1p, const float* __restrict__ b1e,
    float* __restrict__ h2, float* __restrict__ sums)
{
  const int tid = threadIdx.x;
  const int w = tid >> 6, l = tid & 63;
  const int l15 = l & 15, l4 = l >> 4;
  const int blk = blockIdx.x;                 // 512
  const int rowHalf = w & 1, colHalf = w >> 1;
  const int r0 = blk * 32 + 16 * rowHalf;
  const int c0 = 32 * colHalf;
  const int b = blk >> 8;
  const u16* arow_h = h1h + (size_t)(r0 + l15) * 128;
  const u16* arow_l = h1l + (size_t)(r0 + l15) * 128;

  f32x4 acc[2];
  acc[0] = (f32x4){0.f, 0.f, 0.f, 0.f};
  acc[1] = (f32x4){0.f, 0.f, 0.f, 0.f};

  #pragma unroll
  for (int ks = 0; ks < 4; ++ks) {
    bf16x8 ah = *(const bf16x8*)(arow_h + ks * 32 + l4 * 8);
    bf16x8 al_ = *(const bf16x8*)(arow_l + ks * 32 + l4 * 8);
    const u16* bb = w1p + ((size_t)(b * 2) * 16 + ks * 4 + l4) * 512;
    #pragma unroll
    for (int ct = 0; ct < 2; ++ct) {
      const int col = c0 + 16 * ct + l15;
      bf16x8 bh = *(const bf16x8*)(bb + col * 8);
      bf16x8 bl = *(const bf16x8*)(bb + 8192 + col * 8);
      acc[ct] = __builtin_amdgcn_mfma_f32_16x16x32_bf16(ah, bh, acc[ct], 0, 0, 0);
      acc[ct] = __builtin_amdgcn_mfma_f32_16x16x32_bf16(ah, bl, acc[ct], 0, 0, 0);
      acc[ct] = __builtin_amdgcn_mfma_f32_16x16x32_bf16(al_, bh, acc[ct], 0, 0, 0);
    }
  }

  #pragma unroll
  for (int ct = 0; ct < 2; ++ct) {
    const int col = c0 + 16 * ct + l15;
    const float bj = b1e[b * 64 + col];
    float s = 0.f, q = 0.f;
    #pragma unroll
    for (int r = 0; r < 4; ++r) {
      float v = tanh_fast(acc[ct][r] + bj);
      const int row = r0 + 4 * l4 + r;
      h2[(size_t)row * 64 + col] = v;
      s += v; q += v * v;
    }
    s += __shfl_xor(s, 16); s += __shfl_xor(s, 32);
    q += __shfl_xor(q, 16); q += __shfl_xor(q, 32);
    if (l < 16) {
      AADD(&sums[512 + b * 64 + col], s);
      AADD(&sums[640 + b * 64 + col], q);
    }
  }
}

// ---------------- BN2 (inline scale from sums) + bf16 split, norms pre-scaled ------
__global__ __launch_bounds__(256) void k_bn2(
    const float* __restrict__ h2, const float* __restrict__ sums,
    const float* __restrict__ g1, const float* __restrict__ bt1,
    const int* __restrict__ pidx,
    u16* __restrict__ qh, u16* __restrict__ ql, float* __restrict__ qn2,
    u16* __restrict__ kh, u16* __restrict__ kl, float* __restrict__ kn2)
{
  const int tid = threadIdx.x;
  const int r = tid >> 6, o = tid & 63;
  const bool isq = (blockIdx.x < 2048);
  const int b = isq ? 0 : 1;
  float s = sums[512 + b * 64 + o], q = sums[640 + b * 64 + o];
  float m = s * (1.f / 8192.f);
  float v = q * (1.f / 8192.f) - m * m;
  float sc = g1[o] * rsqrtf(v + EPSBN);
  float sh = bt1[o] - m * sc;
  if (isq) {
    const int row = blockIdx.x * 4 + r;
    float vv = sc * h2[(size_t)row * 64 + o] + sh;
    u16 hi = f2bf(vv);
    qh[(size_t)row * 64 + o] = hi;
    ql[(size_t)row * 64 + o] = f2bf(vv - bf2f(hi));
    float sq = vv * vv;
    #pragma unroll
    for (int off = 32; off; off >>= 1) sq += __shfl_xor(sq, off);
    if (o == 0) qn2[row] = SCL * sq;
  } else {
    const int row = (blockIdx.x - 2048) * 4 + r;   // 0..8831
    const int src = pidx[row];
    float vv = 0.f;
    if (src >= 0) vv = sc * h2[(size_t)(NROWS + src) * 64 + o] + sh;
    u16 hi = f2bf(vv);
    kh[(size_t)row * 64 + o] = hi;
    kl[(size_t)row * 64 + o] = f2bf(vv - bf2f(hi));
    float sq = vv * vv;
    #pragma unroll
    for (int off = 32; off; off >>= 1) sq += __shfl_xor(sq, off);
    if (o == 0) kn2[row] = (src >= 0) ? SCL * sq : 1e30f;
  }
}

// ---------------- cdist: 32x32x16 MFMA, dbuf LDS, 1 barrier/tile ----------------
__global__ __launch_bounds__(256, 3) void k_dist(
    const u16* __restrict__ qh, const u16* __restrict__ ql, const float* __restrict__ qn2,
    const u16* __restrict__ kh, const u16* __restrict__ kl, const float* __restrict__ kn2,
    const int* __restrict__ tcls, float* __restrict__ part)
{
  __shared__ u16 bs[2][8192];                       // 2 x 16 KB
  __shared__ float cls_lds[2 * (NCLS + 1) * 64];    // per-colHalf copies
  const int tid = threadIdx.x;
  const int w = tid >> 6, l = tid & 63;
  const int n0 = blockIdx.x * 64;
  const int g = blockIdx.y;
  const int t0 = g * TPG, t1 = t0 + TPG;

  for (int i = tid; i < 2 * (NCLS + 1) * 64; i += 256) cls_lds[i] = 0.f;

  // ---- A fragments (q rows, in regs all kernel) ----
  const int lh = l >> 5;
  const int arow = n0 + 32 * (w >> 1) + (l & 31);
  bf16x8 aH[4], aL[4];
  #pragma unroll
  for (int j = 0; j < 4; ++j) {
    aH[j] = *(const bf16x8*)(qh + (size_t)arow * 64 + j * 16 + 8 * lh);
    aL[j] = *(const bf16x8*)(ql + (size_t)arow * 64 + j * 16 + 8 * lh);
  }
  float qnr[16];
  #pragma unroll
  for (int g4 = 0; g4 < 4; ++g4) {
    f32x4 qv = *(const f32x4*)(qn2 + n0 + 32 * (w >> 1) + 8 * g4 + 4 * lh);
    qnr[4 * g4 + 0] = qv[0]; qnr[4 * g4 + 1] = qv[1];
    qnr[4 * g4 + 2] = qv[2]; qnr[4 * g4 + 3] = qv[3];
  }

  // ---- staging ids: wave w stages (arr=w&1, k-half=w>>1), col = lane ----
  const int sarr = w & 1, shalf = w >> 1;
  const u16* sbase = (sarr ? kl : kh) + (size_t)l * 64 + shalf * 32;
  const int c7l = l & 7;
  char* wb_base = (char*)&bs[0][0] + l * 256 + sarr * 128;
  const int ws0 = (((shalf * 4 + 0) ^ c7l) << 4);
  const int ws1 = (((shalf * 4 + 1) ^ c7l) << 4);
  const int ws2 = (((shalf * 4 + 2) ^ c7l) << 4);
  const int ws3 = (((shalf * 4 + 3) ^ c7l) << 4);

  // ---- B-read ids: wave w computes rows 32*(w>>1), cols 32*(w&1) ----
  const int colL = 32 * (w & 1) + (l & 31);
  const char* rb_base = (const char*)&bs[0][0] + colL * 256;
  const int c7r = colL & 7;

  i32x4 st0, st1, st2, st3;
#define LOADST(TT) do { const u16* sp_ = sbase + (size_t)(TT) * 4096; \
    st0 = *(const i32x4*)(sp_);      st1 = *(const i32x4*)(sp_ + 8);  \
    st2 = *(const i32x4*)(sp_ + 16); st3 = *(const i32x4*)(sp_ + 24); } while (0)
#define WRITEST(PB) do { char* d_ = wb_base + (PB) * 16384; \
    *(i32x4*)(d_ + ws0) = st0; *(i32x4*)(d_ + ws1) = st1; \
    *(i32x4*)(d_ + ws2) = st2; *(i32x4*)(d_ + ws3) = st3; } while (0)
#define FLUSH(CC) do { \
    _Pragma("unroll") for (int r = 0; r < 16; ++r) { \
      run[r] += __shfl_xor(run[r], 1);  run[r] += __shfl_xor(run[r], 2); \
      run[r] += __shfl_xor(run[r], 4);  run[r] += __shfl_xor(run[r], 8); \
      run[r] += __shfl_xor(run[r], 16); } \
    if ((l & 31) == 0) { \
      float* cl_ = cls_lds + (w & 1) * 704 + (CC) * 64 + 32 * (w >> 1) + 4 * lh; \
      _Pragma("unroll") for (int r = 0; r < 16; ++r) cl_[(r & 3) + 8 * (r >> 2)] += run[r]; } \
    _Pragma("unroll") for (int r = 0; r < 16; ++r) run[r] = 0.f; } while (0)

  LOADST(t0);
  WRITEST(0);
  LOADST(t0 + 1);

  float run[16];
  #pragma unroll
  for (int r = 0; r < 16; ++r) run[r] = 0.f;
  int ccur = tcls[t0];
  int p = 0;

  for (int t = t0; t < t1; ++t) {
    __syncthreads();                       // buf[p] staged; prior readers of buf[p^1] done
    if (t + 1 < t1) WRITEST(p ^ 1);
    if (t + 2 < t1) LOADST(t + 2);
    const int c = tcls[t];
    if (c != ccur) { FLUSH(ccur); ccur = c; }
    const float kv = kn2[t * 64 + colL];

    f32x16 acc;
    #pragma unroll
    for (int r = 0; r < 16; ++r) acc[r] = 0.f;
    const char* pb = rb_base + p * 16384;
    #pragma unroll
    for (int j = 0; j < 4; ++j) {
      const int c8 = 2 * j + lh;
      bf16x8 bh  = *(const bf16x8*)(pb + ((c8 ^ c7r) << 4));
      bf16x8 bl_ = *(const bf16x8*)(pb + 128 + ((c8 ^ c7r) << 4));
      acc = __builtin_amdgcn_mfma_f32_32x32x16_bf16(aH[j], bh,  acc, 0, 0, 0);
      acc = __builtin_amdgcn_mfma_f32_32x32x16_bf16(aH[j], bl_, acc, 0, 0, 0);
      acc = __builtin_amdgcn_mfma_f32_32x32x16_bf16(aL[j], bh,  acc, 0, 0, 0);
    }
    #pragma unroll
    for (int r = 0; r < 16; ++r) {
      float d2 = fmaf(SCL2, acc[r], qnr[r] + kv);
      d2 = fmaxf(d2, 2.0813689e-12f);
      run[r] += __builtin_amdgcn_exp2f(-__builtin_amdgcn_sqrtf(d2));
    }
    p ^= 1;
  }
  FLUSH(ccur);
  __syncthreads();

  for (int i = tid; i < (NCLS + 1) * 64; i += 256) {
    const int c = i >> 6, rr = i & 63;
    part[((size_t)g * (NCLS + 1) + c) * NROWS + n0 + rr] = cls_lds[i] + cls_lds[704 + i];
  }
#undef LOADST
#undef WRITEST
#undef FLUSH
}

// ---- finalize ----
__global__ __launch_bounds__(256) void k_final(const float* __restrict__ part,
                                               float* __restrict__ out)
{
  const int n = blockIdx.x * 256 + threadIdx.x;
  float sc[NCLS];
  #pragma unroll
  for (int c = 0; c < NCLS; ++c) sc[c] = 0.f;
  for (int g = 0; g < GY; ++g) {
    #pragma unroll
    for (int c = 0; c < NCLS; ++c)
      sc[c] += part[((size_t)g * (NCLS + 1) + c) * NROWS + n];
  }
  float tot = 0.f;
  #pragma unroll
  for (int c = 0; c < NCLS; ++c) tot += sc[c];
  const float inv = 1.f / tot;
  #pragma unroll
  for (int c = 0; c < NCLS; ++c)
    out[(size_t)n * NCLS + c] = fminf(fmaxf(sc[c] * inv, 0.f), 1.f);
}

extern "C" void kernel_launch(void* const* d_in, const int* in_sizes, int n_in,
                              void* d_out, int out_size, void* d_ws, size_t ws_size,
                              hipStream_t stream) {
  const float* x   = (const float*)d_in[0];
  const float* xn  = (const float*)d_in[1];
  const int*   yn  = (const int*)d_in[2];
  const float* W0  = (const float*)d_in[3];
  const float* b0  = (const float*)d_in[4];
  const float* g0  = (const float*)d_in[5];
  const float* bt0 = (const float*)d_in[6];
  const float* W1  = (const float*)d_in[7];
  const float* b1  = (const float*)d_in[8];
  const float* g1  = (const float*)d_in[9];
  const float* bt1 = (const float*)d_in[10];
  float* out = (float*)d_out;
  float* ws  = (float*)d_ws;

  u16*   w0pp = (u16*)(ws + OFF_W0P);
  u16*   h1hp = (u16*)(ws + OFF_H1H);
  u16*   h1lp = (u16*)(ws + OFF_H1L);
  float* sumsp= ws + OFF_SUM;
  u16*   w1pp = (u16*)(ws + OFF_W1P);
  float* b1ep = ws + OFF_B1E;
  float* h2p  = ws + OFF_H2;
  int*   pidxp= (int*)(ws + OFF_PIDX);
  int*   tclsp= (int*)(ws + OFF_TCLS);
  u16*   qhp  = (u16*)(ws + OFF_QH);
  u16*   qlp  = (u16*)(ws + OFF_QL);
  float* qn2p = ws + OFF_QN2;
  u16*   khp  = (u16*)(ws + OFF_KH);
  u16*   klp  = (u16*)(ws + OFF_KL);
  float* kn2p = ws + OFF_KN2;
  float* partp= ws + OFF_PART;

  k_prep<<<129, 256, 0, stream>>>(W0, yn, w0pp, pidxp, tclsp, sumsp);
  k_layer1<<<512, 256, 0, stream>>>(x, xn, w0pp, b0, h1hp, h1lp, sumsp);
  k_foldp<<<64, 128, 0, stream>>>(W1, b1, g0, bt0, sumsp, w1pp, b1ep);
  k_layer2<<<512, 256, 0, stream>>>(h1hp, h1lp, w1pp, b1ep, h2p, sumsp);
  k_bn2<<<2048 + MPAD / 4, 256, 0, stream>>>(h2p, sumsp, g1, bt1, pidxp,
                                             qhp, qlp, qn2p, khp, klp, kn2p);
  k_dist<<<dim3(128, GY), 256, 0, stream>>>(qhp, qlp, qn2p, khp, klp, kn2p, tclsp, partp);
  k_final<<<32, 256, 0, stream>>>(partp, out);
}